// Round 10
// baseline (1421.367 us; speedup 1.0000x reference)
//
#include <hip/hip_runtime.h>
#include <cfloat>

#define BB 8
#define NN 2048
#define KNN 20
#define EPSV 1e-5f
#define SLOPEV 0.2f

typedef short bf16x8 __attribute__((ext_vector_type(8)));   // 8 bf16 (4 VGPRs)
typedef float f32x4 __attribute__((ext_vector_type(4)));

__device__ __forceinline__ unsigned short f2b(float f) {
    unsigned u = __builtin_bit_cast(unsigned, f);
    unsigned r = (u + 0x7FFFu + ((u >> 16) & 1u)) >> 16;   // RNE
    return (unsigned short)r;
}
__device__ __forceinline__ short4 f2b4(float4 v) {
    short4 r;
    r.x = (short)f2b(v.x); r.y = (short)f2b(v.y);
    r.z = (short)f2b(v.z); r.w = (short)f2b(v.w);
    return r;
}

// ---------------- small prep kernels ----------------

__global__ void transpose0_kernel(const float* __restrict__ x, float* __restrict__ XT0) {
    int e = blockIdx.x * blockDim.x + threadIdx.x;
    if (e >= BB * NN * 3) return;
    int b = e / (NN * 3); int r = e - b * NN * 3; int n = r / 3; int c = r - n * 3;
    XT0[e] = x[((size_t)b * 3 + c) * NN + n];
}

__global__ void wprep_kernel(const float* __restrict__ W, float* __restrict__ WaT,
                             float* __restrict__ WdT, int C, int O) {
    int e = blockIdx.x * blockDim.x + threadIdx.x;
    if (e >= C * O) return;
    int c = e / O, o = e - c * O;
    float a = W[o * 2 * C + c];
    WaT[e] = a;
    WdT[e] = W[o * 2 * C + C + c] - a;
}

// W4 [256][256] -> Wa bf16 [o=256][c=128], Wd bf16 [o=256][c=128]
__global__ void wprep4b_kernel(const float* __restrict__ W, short* __restrict__ Wab,
                               short* __restrict__ Wdb) {
    int e = blockIdx.x * 256 + threadIdx.x;   // 32768 exact
    int o = e >> 7, c = e & 127;
    float a = W[o * 256 + c];
    Wab[e] = (short)f2b(a);
    Wdb[e] = (short)f2b(W[o * 256 + 128 + c] - a);
}

__global__ void w5b_kernel(const float* __restrict__ W5, short* __restrict__ W5b) {
    int e = blockIdx.x * 256 + threadIdx.x;   // 1024*512 exact, same [o][c] layout
    W5b[e] = (short)f2b(W5[e]);
}

// ---------------- per-point squared norm (matches dot-product partial order) ----

template <int C>
__global__ void xx_kernel(const float* __restrict__ XT, float* __restrict__ xx) {
    int e = blockIdx.x * blockDim.x + threadIdx.x;
    if (e >= BB * NN) return;
    const float* p = &XT[(size_t)e * C];
    float s;
    if constexpr (C % 4 == 0) {
        float s0 = 0, s1 = 0, s2 = 0, s3 = 0;
        for (int c = 0; c < C; c += 4) {
            float4 v = *(const float4*)(p + c);
            s0 += v.x * v.x; s1 += v.y * v.y; s2 += v.z * v.z; s3 += v.w * v.w;
        }
        s = (s0 + s1) + (s2 + s3);
    } else {
        s = p[0] * p[0];
        for (int c = 1; c < C; ++c) s += p[c] * p[c];
    }
    xx[e] = s;
}

// ---------------- KNN: tiled distance GEMM + register selection ----------------

template <int C>
__global__ __launch_bounds__(256) void knn_dist_kernel(
    const float* __restrict__ XC,   // [B][C][N]
    const float* __restrict__ XT,   // [B][N][C]
    const float* __restrict__ xx,   // [B][N]
    float* __restrict__ pd2,        // [2][N][N]
    int b0) {
    constexpr int BK = 16;
    __shared__ float As[BK][68];    // [c][n] (transposed on store)
    __shared__ alignas(16) float Bs[BK][64];   // [c][m]
    int mt = blockIdx.x, nt = blockIdx.y, bz = blockIdx.z;
    int b = b0 + bz;
    int n0 = nt * 64, m0 = mt * 64;
    int tid = threadIdx.x;
    int tn = tid >> 4, tm = tid & 15;
    float P[4][4][4];
    #pragma unroll
    for (int cl = 0; cl < 4; ++cl)
        #pragma unroll
        for (int i = 0; i < 4; ++i)
            #pragma unroll
            for (int j = 0; j < 4; ++j) P[cl][i][j] = 0.f;

    int arow = tid >> 2, acq = tid & 3;
    int brow = tid >> 4, bmq = tid & 15;
    for (int kb = 0; kb < C / BK; ++kb) {
        if (kb) __syncthreads();
        float4 av = *(const float4*)&XT[((size_t)b * NN + n0 + arow) * C + kb * BK + acq * 4];
        As[acq * 4 + 0][arow] = av.x; As[acq * 4 + 1][arow] = av.y;
        As[acq * 4 + 2][arow] = av.z; As[acq * 4 + 3][arow] = av.w;
        *(float4*)&Bs[brow][bmq * 4] =
            *(const float4*)&XC[((size_t)b * C + kb * BK + brow) * NN + m0 + bmq * 4];
        __syncthreads();
        #pragma unroll
        for (int c = 0; c < BK; ++c) {
            float4 a = *(const float4*)&As[c][tn * 4];
            float4 bv = *(const float4*)&Bs[c][tm * 4];
            int cl = c & 3;
            P[cl][0][0] += a.x * bv.x; P[cl][0][1] += a.x * bv.y; P[cl][0][2] += a.x * bv.z; P[cl][0][3] += a.x * bv.w;
            P[cl][1][0] += a.y * bv.x; P[cl][1][1] += a.y * bv.y; P[cl][1][2] += a.y * bv.z; P[cl][1][3] += a.y * bv.w;
            P[cl][2][0] += a.z * bv.x; P[cl][2][1] += a.z * bv.y; P[cl][2][2] += a.z * bv.z; P[cl][2][3] += a.z * bv.w;
            P[cl][3][0] += a.w * bv.x; P[cl][3][1] += a.w * bv.y; P[cl][3][2] += a.w * bv.z; P[cl][3][3] += a.w * bv.w;
        }
    }
    float4 xm = *(const float4*)&xx[(size_t)b * NN + m0 + tm * 4];
    #pragma unroll
    for (int i = 0; i < 4; ++i) {
        float xrn = xx[(size_t)b * NN + n0 + tn * 4 + i];
        float4 pd;
        float in0 = (P[0][i][0] + P[1][i][0]) + (P[2][i][0] + P[3][i][0]);
        float in1 = (P[0][i][1] + P[1][i][1]) + (P[2][i][1] + P[3][i][1]);
        float in2 = (P[0][i][2] + P[1][i][2]) + (P[2][i][2] + P[3][i][2]);
        float in3 = (P[0][i][3] + P[1][i][3]) + (P[2][i][3] + P[3][i][3]);
        pd.x = (2.0f * in0 - xrn) - xm.x;
        pd.y = (2.0f * in1 - xrn) - xm.y;
        pd.z = (2.0f * in2 - xrn) - xm.z;
        pd.w = (2.0f * in3 - xrn) - xm.w;
        *(float4*)&pd2[((size_t)bz * NN + n0 + tn * 4 + i) * NN + m0 + tm * 4] = pd;
    }
}

// strict > keeps earliest-inserted (lowest m) among equal values
#define INS(val, mm) do { \
    float _v = (val); int _m = (mm); \
    bool b1 = _v > v1, b2 = _v > v2, b3 = _v > v3, b4 = _v > v4; \
    i4 = b3 ? i3 : (b4 ? _m : i4);  v4 = b3 ? v3 : (b4 ? _v : v4); \
    i3 = b2 ? i2 : (b3 ? _m : i3);  v3 = b2 ? v2 : (b3 ? _v : v3); \
    i2 = b1 ? i1 : (b2 ? _m : i2);  v2 = b1 ? v1 : (b2 ? _v : v2); \
    i1 = b1 ? _m : i1;              v1 = b1 ? _v : v1; \
} while (0)

__device__ __forceinline__ void sel20_reg(const float4* pv, int lane, int* outp) {
    float v1 = -FLT_MAX, v2 = -FLT_MAX, v3 = -FLT_MAX, v4 = -FLT_MAX;
    int i1 = 0x7FFFFFFF, i2 = 0x7FFFFFFF, i3 = 0x7FFFFFFF, i4 = 0x7FFFFFFF;
    unsigned rm = 0;
    #pragma unroll
    for (int j = 0; j < 8; ++j) {
        int m0 = 4 * lane + 256 * j;
        INS(pv[j].x, m0); INS(pv[j].y, m0 + 1); INS(pv[j].z, m0 + 2); INS(pv[j].w, m0 + 3);
    }
    int depth = 4;
    for (int it = 0; it < KNN; ++it) {
        float bv = v1;
        #pragma unroll
        for (int off = 1; off < 64; off <<= 1) bv = fmaxf(bv, __shfl_xor(bv, off));
        int cand = (v1 == bv) ? i1 : 0x7FFFFFFF;
        int bi = cand;
        #pragma unroll
        for (int off = 1; off < 64; off <<= 1) bi = min(bi, __shfl_xor(bi, off));
        if (lane == 0) outp[it] = bi;
        if (v1 == bv && i1 == bi) {       // unique owner
            rm |= 1u << ((((unsigned)bi >> 6) & 0x1C) | ((unsigned)bi & 3));  // slot 4j+q
            v1 = v2; i1 = i2; v2 = v3; i2 = i3; v3 = v4; i3 = i4;
            v4 = -FLT_MAX; i4 = 0x7FFFFFFF;
            if (--depth == 0) {           // cache exhausted: exact rescan (rare)
                v1 = v2 = v3 = v4 = -FLT_MAX;
                i1 = i2 = i3 = i4 = 0x7FFFFFFF;
                #pragma unroll
                for (int j = 0; j < 8; ++j) {
                    int m0 = 4 * lane + 256 * j;
                    if (!(rm & (1u << (4 * j + 0)))) INS(pv[j].x, m0);
                    if (!(rm & (1u << (4 * j + 1)))) INS(pv[j].y, m0 + 1);
                    if (!(rm & (1u << (4 * j + 2)))) INS(pv[j].z, m0 + 2);
                    if (!(rm & (1u << (4 * j + 3)))) INS(pv[j].w, m0 + 3);
                }
                depth = 4;
            }
        }
    }
}

__global__ __launch_bounds__(256) void knn_sel_kernel(
    const float* __restrict__ pd2, int* __restrict__ idxb, int b0) {
    int tid = threadIdx.x, w = tid >> 6, lane = tid & 63;
    int rg = blockIdx.x * 4 + w;          // 0..4095 (2 batches)
    int bz = rg >> 11, n = rg & (NN - 1);
    const float* row = pd2 + ((size_t)bz * NN + n) * NN;
    float4 pv[8];
    #pragma unroll
    for (int j = 0; j < 8; ++j) pv[j] = *(const float4*)&row[4 * lane + 256 * j];
    int* outp = idxb + ((size_t)(b0 + bz) * NN + n) * KNN;
    sel20_reg(pv, lane, outp);
}

// Layer-1 (C=3) fused: pd computed inline in registers, same selection.
__global__ __launch_bounds__(256) void knn_c3_kernel(
    const float* __restrict__ XC,   // x: [B][3][N]
    const float* __restrict__ XT,   // XT0: [B][N][3]
    const float* __restrict__ xx, int* __restrict__ idxb) {
    int tid = threadIdx.x, w = tid >> 6, lane = tid & 63;
    int rg = blockIdx.x * 4 + w;          // 0..16383
    int b = rg >> 11, n = rg & (NN - 1);
    const float* xt0 = XT + ((size_t)b * NN + n) * 3;
    float s0 = xt0[0], s1 = xt0[1], s2 = xt0[2];
    float xrn = xx[(size_t)b * NN + n];
    float4 pv[8];
    #pragma unroll
    for (int j = 0; j < 8; ++j) {
        int m0 = 4 * lane + 256 * j;
        float4 v0 = *(const float4*)&XC[((size_t)b * 3 + 0) * NN + m0];
        float4 v1 = *(const float4*)&XC[((size_t)b * 3 + 1) * NN + m0];
        float4 v2 = *(const float4*)&XC[((size_t)b * 3 + 2) * NN + m0];
        float4 xm = *(const float4*)&xx[(size_t)b * NN + m0];
        float4 in;
        in.x = v0.x * s0; in.x += v1.x * s1; in.x += v2.x * s2;
        in.y = v0.y * s0; in.y += v1.y * s1; in.y += v2.y * s2;
        in.z = v0.z * s0; in.z += v1.z * s1; in.z += v2.z * s2;
        in.w = v0.w * s0; in.w += v1.w * s1; in.w += v2.w * s2;
        pv[j].x = (2.0f * in.x - xrn) - xm.x;
        pv[j].y = (2.0f * in.y - xrn) - xm.y;
        pv[j].z = (2.0f * in.z - xrn) - xm.z;
        pv[j].w = (2.0f * in.w - xrn) - xm.w;
    }
    int* outp = idxb + ((size_t)b * NN + n) * KNN;
    sel20_reg(pv, lane, outp);
}
#undef INS

// ---------------- dense T1/T2 precompute (fp32, layers 1-3) ----------------

template <int C, int O>
__global__ __launch_bounds__(256) void t1t2_gemm_kernel(
    const float* __restrict__ XT, const float* __restrict__ WaT,
    const float* __restrict__ WdT, float* __restrict__ T1, float* __restrict__ T2) {
    constexpr int CP = (C < 4) ? 4 : C;
    __shared__ alignas(16) float xt[64][CP];
    int p0 = blockIdx.x * 64;
    int tid = threadIdx.x;
    if constexpr (C % 4 == 0) {
        for (int e = tid; e < 64 * (C / 4); e += 256) {
            int r = e / (C / 4), q = e - r * (C / 4);
            *(float4*)&xt[r][q * 4] = *(const float4*)&XT[((size_t)p0 + r) * C + q * 4];
        }
    } else {
        for (int e = tid; e < 64 * C; e += 256) {
            int r = e / C, c = e - r * C;
            xt[r][c] = XT[((size_t)p0 + r) * C + c];
        }
    }
    __syncthreads();
    {
        constexpr int OQ = O / 4;
        constexpr int PS = 256 / OQ;
        constexpr int PPT = 64 / PS;
        int oq = tid % OQ, ps = tid / OQ;
        int o0 = oq * 4;
        float acc[PPT][4];
        #pragma unroll
        for (int t = 0; t < PPT; ++t) { acc[t][0] = 0; acc[t][1] = 0; acc[t][2] = 0; acc[t][3] = 0; }
        if constexpr (C % 4 == 0) {
            for (int c = 0; c < C; c += 4) {
                float4 w0 = *(const float4*)&WaT[(c + 0) * O + o0];
                float4 w1 = *(const float4*)&WaT[(c + 1) * O + o0];
                float4 w2 = *(const float4*)&WaT[(c + 2) * O + o0];
                float4 w3 = *(const float4*)&WaT[(c + 3) * O + o0];
                #pragma unroll
                for (int t = 0; t < PPT; ++t) {
                    float4 nv = *(const float4*)&xt[ps + t * PS][c];
                    acc[t][0] += nv.x * w0.x + nv.y * w1.x + nv.z * w2.x + nv.w * w3.x;
                    acc[t][1] += nv.x * w0.y + nv.y * w1.y + nv.z * w2.y + nv.w * w3.y;
                    acc[t][2] += nv.x * w0.z + nv.y * w1.z + nv.z * w2.z + nv.w * w3.z;
                    acc[t][3] += nv.x * w0.w + nv.y * w1.w + nv.z * w2.w + nv.w * w3.w;
                }
            }
        } else {
            for (int c = 0; c < C; ++c) {
                float4 w = *(const float4*)&WaT[c * O + o0];
                #pragma unroll
                for (int t = 0; t < PPT; ++t) {
                    float nv = xt[ps + t * PS][c];
                    acc[t][0] += nv * w.x; acc[t][1] += nv * w.y;
                    acc[t][2] += nv * w.z; acc[t][3] += nv * w.w;
                }
            }
        }
        #pragma unroll
        for (int t = 0; t < PPT; ++t)
            *(float4*)&T1[((size_t)p0 + ps + t * PS) * O + o0] =
                make_float4(acc[t][0], acc[t][1], acc[t][2], acc[t][3]);
    }
    {
        constexpr int PS2 = 256 / O;
        constexpr int PPT2 = 64 / PS2;
        int o = tid % O, ps = tid / O;
        float s[PPT2];
        #pragma unroll
        for (int t = 0; t < PPT2; ++t) s[t] = 0.f;
        for (int c = 0; c < C; ++c) {
            float w = WdT[c * O + o];
            #pragma unroll
            for (int t = 0; t < PPT2; ++t) s[t] += w * xt[ps + t * PS2][c];
        }
        #pragma unroll
        for (int t = 0; t < PPT2; ++t) T2[((size_t)p0 + ps + t * PS2) * O + o] = s[t];
    }
}

// ---------------- edge gather-reduce (DETERMINISTIC stats) --------

template <int O, int G>
__global__ __launch_bounds__(256) void edge_reduce_kernel(
    const float* __restrict__ T1, const float* __restrict__ T2,
    const int* __restrict__ idxb,
    float* __restrict__ ymaxb, float* __restrict__ yminb, float* __restrict__ stP) {
    constexpr int OQ = O / 4;
    constexpr int PTS = 256 / OQ;
    __shared__ int sidx[PTS][KNN];
    __shared__ alignas(16) float red[2][PTS][O];   // 2*PTS*O = 2048 floats
    int blk = blockIdx.x, tid = threadIdx.x;
    int oq = tid % OQ, ps = tid / OQ;
    int o0 = oq * 4;
    float4 as = make_float4(0, 0, 0, 0), aq = make_float4(0, 0, 0, 0);
    for (int g = 0; g < G; ++g) {
        int pbase = (blk * G + g) * PTS;
        if (g) __syncthreads();
        for (int e = tid; e < PTS * KNN; e += 256)
            sidx[e / KNN][e % KNN] = idxb[(size_t)(pbase + e / KNN) * KNN + (e % KNN)];
        __syncthreads();
        int p = pbase + ps;
        int b = p >> 11;
        float4 t2v = *(const float4*)&T2[(size_t)p * O + o0];
        float4 vmax = make_float4(-FLT_MAX, -FLT_MAX, -FLT_MAX, -FLT_MAX);
        float4 vmin = make_float4(FLT_MAX, FLT_MAX, FLT_MAX, FLT_MAX);
        float4 vs = make_float4(0, 0, 0, 0), vq = make_float4(0, 0, 0, 0);
        #pragma unroll 4
        for (int k = 0; k < KNN; ++k) {
            int r = (b << 11) + sidx[ps][k];
            float4 t1v = *(const float4*)&T1[(size_t)r * O + o0];
            float yx = t1v.x + t2v.x, yy = t1v.y + t2v.y;
            float yz = t1v.z + t2v.z, yw = t1v.w + t2v.w;
            vmax.x = fmaxf(vmax.x, yx); vmax.y = fmaxf(vmax.y, yy);
            vmax.z = fmaxf(vmax.z, yz); vmax.w = fmaxf(vmax.w, yw);
            vmin.x = fminf(vmin.x, yx); vmin.y = fminf(vmin.y, yy);
            vmin.z = fminf(vmin.z, yz); vmin.w = fminf(vmin.w, yw);
            vs.x += yx; vs.y += yy; vs.z += yz; vs.w += yw;
            vq.x += yx * yx; vq.y += yy * yy; vq.z += yz * yz; vq.w += yw * yw;
        }
        *(float4*)&ymaxb[(size_t)p * O + o0] = vmax;
        *(float4*)&yminb[(size_t)p * O + o0] = vmin;
        as.x += vs.x; as.y += vs.y; as.z += vs.z; as.w += vs.w;
        aq.x += vq.x; aq.y += vq.y; aq.z += vq.z; aq.w += vq.w;
    }
    __syncthreads();
    *(float4*)&red[0][ps][o0] = as;
    *(float4*)&red[1][ps][o0] = aq;
    __syncthreads();
    for (int e = tid; e < 2 * O; e += 256) {
        int pl = e / O, oo = e - pl * O;
        float s = red[pl][0][oo];
        #pragma unroll 4
        for (int j = 1; j < PTS; ++j) s += red[pl][j][oo];
        stP[(size_t)blk * 2 * O + e] = s;
    }
}

// ---------------- T = XT3 . W (bf16 MFMA), all points; used for T1_4 and T2_4 ----

__global__ __launch_bounds__(256) void t2_mfma_kernel(
    const float* __restrict__ XT3, const short* __restrict__ Wdb, float* __restrict__ T2) {
    __shared__ alignas(16) short A[16][136];
    int blk = blockIdx.x;           // BB*NN/16 = 1024
    int tid = threadIdx.x, w = tid >> 6, lane = tid & 63;
    int n0g = blk * 16;
    for (int ch = tid; ch < 512; ch += 256) {
        int r = ch >> 5, c4 = (ch & 31) << 2;
        float4 v = *(const float4*)&XT3[((size_t)n0g + r) * 128 + c4];
        *(short4*)&A[r][c4] = f2b4(v);
    }
    __syncthreads();
    int arow = lane & 15, aq = lane >> 4;
    bf16x8 af[4];
    #pragma unroll
    for (int ks = 0; ks < 4; ++ks)
        af[ks] = *(const bf16x8*)&A[arow][ks * 32 + aq * 8];
    for (int t = 0; t < 4; ++t) {
        int nt = w * 4 + t;
        f32x4 acc = {0.f, 0.f, 0.f, 0.f};
        const short* bp = Wdb + (size_t)(nt * 16 + arow) * 128 + aq * 8;
        #pragma unroll
        for (int ks = 0; ks < 4; ++ks)
            acc = __builtin_amdgcn_mfma_f32_16x16x32_bf16(af[ks], *(const bf16x8*)(bp + ks * 32), acc, 0, 0, 0);
        #pragma unroll
        for (int r = 0; r < 4; ++r)
            T2[((size_t)n0g + aq * 4 + r) * 256 + nt * 16 + arow] = acc[r];
    }
}

// ---------------- BN finalize (fixed-order over per-block partials) ----------

__global__ void finalize_stats_kernel(const float* __restrict__ stP, const float* __restrict__ gg,
                                      const float* __restrict__ bb, float* __restrict__ scsh,
                                      int O, int nblk, float invM) {
    int o = blockIdx.x * blockDim.x + threadIdx.x;
    if (o >= O) return;
    float sa[8] = {0, 0, 0, 0, 0, 0, 0, 0}, qa[8] = {0, 0, 0, 0, 0, 0, 0, 0};
    int cp = 0;
    for (; cp + 8 <= nblk; cp += 8) {
        #pragma unroll
        for (int j = 0; j < 8; ++j) {
            sa[j] += stP[(size_t)(cp + j) * 2 * O + o];
            qa[j] += stP[(size_t)(cp + j) * 2 * O + O + o];
        }
    }
    for (; cp < nblk; ++cp) {
        sa[0] += stP[(size_t)cp * 2 * O + o];
        qa[0] += stP[(size_t)cp * 2 * O + O + o];
    }
    float s1 = ((sa[0] + sa[1]) + (sa[2] + sa[3])) + ((sa[4] + sa[5]) + (sa[6] + sa[7]));
    float s2 = ((qa[0] + qa[1]) + (qa[2] + qa[3])) + ((qa[4] + qa[5]) + (qa[6] + qa[7]));
    float mean = s1 * invM;
    float var = s2 * invM - mean * mean;
    float scale = gg[o] * rsqrtf(var + EPSV);
    float shift = bb[o] - mean * scale;
    scsh[o] = scale; scsh[O + o] = shift;
}

__global__ void edge_passB_kernel(const float* __restrict__ ymaxb, const float* __restrict__ yminb,
                                  const float* __restrict__ scsh, float* __restrict__ XTout,
                                  float* __restrict__ XCout, int O, int total) {
    int e = blockIdx.x * blockDim.x + threadIdx.x;
    if (e >= total) return;
    int o = e & (O - 1);
    float sc = scsh[o], sh = scsh[O + o];
    float y = (sc >= 0.0f) ? ymaxb[e] : yminb[e];   // monotone-affine max/min trick
    float z = sc * y + sh;
    float r = (z > 0.0f) ? z : SLOPEV * z;
    XTout[e] = r;
    if (XCout) {
        int n = (e / O) & (NN - 1);
        int bb_ = e / (O * NN);
        XCout[((size_t)bb_ * O + o) * NN + n] = r;
    }
}

// ---------------- final 512->1024 (bf16 MFMA, 16 pts/block, dual-nt ILP) -----

__device__ __forceinline__ void stage_cat16_b(short (*A)[520], const float* __restrict__ XT1,
                                              const float* __restrict__ XT2, const float* __restrict__ XT3,
                                              const float* __restrict__ XT4, int n0g, int tid) {
    for (int ch = tid; ch < 16 * 16; ch += 256) { int r = ch >> 4, c4 = (ch & 15) << 2;
        *(short4*)&A[r][c4]       = f2b4(*(const float4*)&XT1[((size_t)n0g + r) * 64 + c4]); }
    for (int ch = tid; ch < 16 * 16; ch += 256) { int r = ch >> 4, c4 = (ch & 15) << 2;
        *(short4*)&A[r][64 + c4]  = f2b4(*(const float4*)&XT2[((size_t)n0g + r) * 64 + c4]); }
    for (int ch = tid; ch < 16 * 32; ch += 256) { int r = ch >> 5, c4 = (ch & 31) << 2;
        *(short4*)&A[r][128 + c4] = f2b4(*(const float4*)&XT3[((size_t)n0g + r) * 128 + c4]); }
    for (int ch = tid; ch < 16 * 64; ch += 256) { int r = ch >> 6, c4 = (ch & 63) << 2;
        *(short4*)&A[r][256 + c4] = f2b4(*(const float4*)&XT4[((size_t)n0g + r) * 256 + c4]); }
}

// Pass A: block-partial BN stats, non-atomic (slot = blk = point-tile index).
__global__ __launch_bounds__(256) void final_mfmaA_kernel(
    const float* __restrict__ XT1, const float* __restrict__ XT2, const float* __restrict__ XT3,
    const float* __restrict__ XT4, const short* __restrict__ W5b, float* __restrict__ stP5) {
    __shared__ alignas(16) short A[16][520];
    int blk = blockIdx.x;           // BB*NN/16 = 1024
    int tid = threadIdx.x, w = tid >> 6, lane = tid & 63;
    int n0g = blk * 16;
    stage_cat16_b(A, XT1, XT2, XT3, XT4, n0g, tid);
    __syncthreads();
    int arow = lane & 15, aq = lane >> 4;
    bf16x8 af[16];
    #pragma unroll
    for (int ks = 0; ks < 16; ++ks)
        af[ks] = *(const bf16x8*)&A[arow][ks * 32 + aq * 8];
    float* bp5 = stP5 + (size_t)blk * 2048;
    for (int tp = 0; tp < 8; ++tp) {
        int nt0 = w * 16 + 2 * tp, nt1 = nt0 + 1;
        f32x4 acc0 = {0.f, 0.f, 0.f, 0.f}, acc1 = {0.f, 0.f, 0.f, 0.f};
        const short* bp0 = W5b + (size_t)(nt0 * 16 + arow) * 512 + aq * 8;
        const short* bp1 = W5b + (size_t)(nt1 * 16 + arow) * 512 + aq * 8;
        #pragma unroll
        for (int ks = 0; ks < 16; ++ks) {
            bf16x8 b0 = *(const bf16x8*)(bp0 + ks * 32);
            bf16x8 b1 = *(const bf16x8*)(bp1 + ks * 32);
            acc0 = __builtin_amdgcn_mfma_f32_16x16x32_bf16(af[ks], b0, acc0, 0, 0, 0);
            acc1 = __builtin_amdgcn_mfma_f32_16x16x32_bf16(af[ks], b1, acc1, 0, 0, 0);
        }
        #pragma unroll
        for (int half = 0; half < 2; ++half) {
            f32x4 acc = half ? acc1 : acc0;
            int nt = half ? nt1 : nt0;
            float ls = (acc[0] + acc[1]) + (acc[2] + acc[3]);
            float lsq = (acc[0] * acc[0] + acc[1] * acc[1]) + (acc[2] * acc[2] + acc[3] * acc[3]);
            ls += __shfl_xor(ls, 16); ls += __shfl_xor(ls, 32);
            lsq += __shfl_xor(lsq, 16); lsq += __shfl_xor(lsq, 32);
            if (lane < 16) {
                int o = nt * 16 + lane;
                bp5[o] = ls; bp5[1024 + o] = lsq;
            }
        }
    }
}

__global__ __launch_bounds__(256) void final_mfmaB_kernel(
    const float* __restrict__ XT1, const float* __restrict__ XT2, const float* __restrict__ XT3,
    const float* __restrict__ XT4, const short* __restrict__ W5b, const float* __restrict__ scsh,
    float* __restrict__ pmax, float* __restrict__ psum) {
    __shared__ alignas(16) short A[16][520];
    int blk = blockIdx.x;           // 1024
    int tid = threadIdx.x, w = tid >> 6, lane = tid & 63;
    int n0g = blk * 16;
    stage_cat16_b(A, XT1, XT2, XT3, XT4, n0g, tid);
    __syncthreads();
    int arow = lane & 15, aq = lane >> 4;
    bf16x8 af[16];
    #pragma unroll
    for (int ks = 0; ks < 16; ++ks)
        af[ks] = *(const bf16x8*)&A[arow][ks * 32 + aq * 8];
    for (int tp = 0; tp < 8; ++tp) {
        int nt0 = w * 16 + 2 * tp, nt1 = nt0 + 1;
        f32x4 acc0 = {0.f, 0.f, 0.f, 0.f}, acc1 = {0.f, 0.f, 0.f, 0.f};
        const short* bp0 = W5b + (size_t)(nt0 * 16 + arow) * 512 + aq * 8;
        const short* bp1 = W5b + (size_t)(nt1 * 16 + arow) * 512 + aq * 8;
        #pragma unroll
        for (int ks = 0; ks < 16; ++ks) {
            bf16x8 b0 = *(const bf16x8*)(bp0 + ks * 32);
            bf16x8 b1 = *(const bf16x8*)(bp1 + ks * 32);
            acc0 = __builtin_amdgcn_mfma_f32_16x16x32_bf16(af[ks], b0, acc0, 0, 0, 0);
            acc1 = __builtin_amdgcn_mfma_f32_16x16x32_bf16(af[ks], b1, acc1, 0, 0, 0);
        }
        #pragma unroll
        for (int half = 0; half < 2; ++half) {
            f32x4 acc = half ? acc1 : acc0;
            int nt = half ? nt1 : nt0;
            int o = nt * 16 + arow;
            float sc = scsh[o], sh = scsh[1024 + o];
            float lmax = -FLT_MAX, lsm = 0.f;
            #pragma unroll
            for (int r = 0; r < 4; ++r) {
                float z = fmaf(sc, acc[r], sh);
                float l = (z > 0.0f) ? z : SLOPEV * z;
                lmax = fmaxf(lmax, l); lsm += l;
            }
            lmax = fmaxf(lmax, __shfl_xor(lmax, 16));
            lmax = fmaxf(lmax, __shfl_xor(lmax, 32));
            lsm += __shfl_xor(lsm, 16); lsm += __shfl_xor(lsm, 32);
            if (lane < 16) {
                pmax[(size_t)blk * 1024 + nt * 16 + lane] = lmax;
                psum[(size_t)blk * 1024 + nt * 16 + lane] = lsm;
            }
        }
    }
}

__global__ void final_passC_kernel(const float* __restrict__ pmax, const float* __restrict__ psum,
                                   float* __restrict__ out) {
    int e = blockIdx.x * blockDim.x + threadIdx.x;
    if (e >= BB * 1024) return;
    int b = e >> 10, o = e & 1023;
    float mx = -FLT_MAX, sm = 0;
    for (int j = 0; j < NN / 16; ++j) {
        size_t p = ((size_t)(b * (NN / 16) + j)) * 1024 + o;
        mx = fmaxf(mx, pmax[p]);
        sm += psum[p];
    }
    out[b * 2048 + o] = mx;
    out[b * 2048 + 1024 + o] = sm * (1.0f / NN);
}

// ---------------- launch ----------------

extern "C" void kernel_launch(void* const* d_in, const int* in_sizes, int n_in,
                              void* d_out, int out_size, void* d_ws, size_t ws_size,
                              hipStream_t stream) {
    const float* x  = (const float*)d_in[0];
    const float* W1 = (const float*)d_in[1];
    const float* W2 = (const float*)d_in[2];
    const float* W3 = (const float*)d_in[3];
    const float* W4 = (const float*)d_in[4];
    const float* W5 = (const float*)d_in[5];
    const float* g1 = (const float*)d_in[6];  const float* b1 = (const float*)d_in[7];
    const float* g2 = (const float*)d_in[8];  const float* b2 = (const float*)d_in[9];
    const float* g3 = (const float*)d_in[10]; const float* b3 = (const float*)d_in[11];
    const float* g4 = (const float*)d_in[12]; const float* b4 = (const float*)d_in[13];
    const float* g5 = (const float*)d_in[14]; const float* b5 = (const float*)d_in[15];

    float* ws = (float*)d_ws;
    size_t off = 0;
    float* XT0 = ws + off; off += (size_t)BB * NN * 3;
    float* XT1 = ws + off; off += (size_t)BB * NN * 64;
    float* XT2 = ws + off; off += (size_t)BB * NN * 64;
    float* XT3 = ws + off; off += (size_t)BB * NN * 128;
    float* XT4 = ws + off; off += (size_t)BB * NN * 256;
    float* XC1 = ws + off; off += (size_t)BB * NN * 64;
    float* XC2 = ws + off; off += (size_t)BB * NN * 64;
    float* XC3 = ws + off; off += (size_t)BB * NN * 128;
    float* ymax = ws + off; off += (size_t)BB * NN * 256;
    float* ymin = ws + off; off += (size_t)BB * NN * 256;
    int*   idxb = (int*)(ws + off); off += (size_t)BB * NN * KNN;
    float* xxb = ws + off; off += (size_t)BB * NN;
    float* WaT = ws + off; off += 128 * 256;
    float* WdT = ws + off; off += 128 * 256;
    short* Wa4b = (short*)(ws + off); off += 256 * 128 / 2;
    short* Wd4b = (short*)(ws + off); off += 256 * 128 / 2;
    short* W5b  = (short*)(ws + off); off += 1024 * 512 / 2;
    float* stP = ws + off; off += 2048 * 256;          // per-block stat partials (max 524288)
    float* sc1 = ws + off; off += 2 * 64;
    float* sc2 = ws + off; off += 2 * 64;
    float* sc3 = ws + off; off += 2 * 128;
    float* sc4 = ws + off; off += 2 * 256;
    float* sc5 = ws + off; off += 2 * 1024;
    // aliases (lifetime-disjoint):
    float* T1f = XT4;                                  // layers 1-3 T1 (<=8MB)
    float* T2f = XT4 + (size_t)BB * NN * 128;          // layers 1-3 T2 (<=8MB)
    float* T1_4 = XT4;                                 // layer-4 T1 (16MB), consumed before passB writes XT4
    float* T2_4 = XC1;                                 // layer-4 T2 (16MB = XC1..3), dead after layer-4 knn
    float* pd2 = ymax;                                 // 2-batch pd tile (33.5MB = ymax+ymin)
    float* stP5 = ymax;                                // final-layer stat partials (2M floats), ymax dead then
    float* pmax = ymax;                                // final partials (after finalize consumed stP5)
    float* psum = ymin;

    transpose0_kernel<<<(BB * NN * 3 + 255) / 256, 256, 0, stream>>>(x, XT0);

    dim3 dgrid(NN / 64, NN / 64, 2);

    // layer 1: C=3 -> O=64   (x itself is the channel-major XC0)
    wprep_kernel<<<(3 * 64 + 255) / 256, 256, 0, stream>>>(W1, WaT, WdT, 3, 64);
    xx_kernel<3><<<BB * NN / 256, 256, 0, stream>>>(XT0, xxb);
    knn_c3_kernel<<<BB * NN / 4, 256, 0, stream>>>(x, XT0, xxb, idxb);
    t1t2_gemm_kernel<3, 64><<<BB * NN / 64, 256, 0, stream>>>(XT0, WaT, WdT, T1f, T2f);
    edge_reduce_kernel<64, 1><<<BB * NN / 16, 256, 0, stream>>>(T1f, T2f, idxb, ymax, ymin, stP);
    finalize_stats_kernel<<<1, 64, 0, stream>>>(stP, g1, b1, sc1, 64, BB * NN / 16, 1.0f / ((float)BB * NN * KNN));
    edge_passB_kernel<<<BB * NN * 64 / 256, 256, 0, stream>>>(ymax, ymin, sc1, XT1, XC1, 64, BB * NN * 64);

    // layer 2: C=64 -> O=64
    wprep_kernel<<<(64 * 64 + 255) / 256, 256, 0, stream>>>(W2, WaT, WdT, 64, 64);
    xx_kernel<64><<<BB * NN / 256, 256, 0, stream>>>(XT1, xxb);
    for (int p = 0; p < 4; ++p) {
        knn_dist_kernel<64><<<dgrid, 256, 0, stream>>>(XC1, XT1, xxb, pd2, 2 * p);
        knn_sel_kernel<<<2 * NN / 4, 256, 0, stream>>>(pd2, idxb, 2 * p);
    }
    t1t2_gemm_kernel<64, 64><<<BB * NN / 64, 256, 0, stream>>>(XT1, WaT, WdT, T1f, T2f);
    edge_reduce_kernel<64, 1><<<BB * NN / 16, 256, 0, stream>>>(T1f, T2f, idxb, ymax, ymin, stP);
    finalize_stats_kernel<<<1, 64, 0, stream>>>(stP, g2, b2, sc2, 64, BB * NN / 16, 1.0f / ((float)BB * NN * KNN));
    edge_passB_kernel<<<BB * NN * 64 / 256, 256, 0, stream>>>(ymax, ymin, sc2, XT2, XC2, 64, BB * NN * 64);

    // layer 3: C=64 -> O=128
    wprep_kernel<<<(64 * 128 + 255) / 256, 256, 0, stream>>>(W3, WaT, WdT, 64, 128);
    xx_kernel<64><<<BB * NN / 256, 256, 0, stream>>>(XT2, xxb);
    for (int p = 0; p < 4; ++p) {
        knn_dist_kernel<64><<<dgrid, 256, 0, stream>>>(XC2, XT2, xxb, pd2, 2 * p);
        knn_sel_kernel<<<2 * NN / 4, 256, 0, stream>>>(pd2, idxb, 2 * p);
    }
    t1t2_gemm_kernel<64, 128><<<BB * NN / 64, 256, 0, stream>>>(XT2, WaT, WdT, T1f, T2f);
    edge_reduce_kernel<128, 1><<<BB * NN / 8, 256, 0, stream>>>(T1f, T2f, idxb, ymax, ymin, stP);
    finalize_stats_kernel<<<1, 128, 0, stream>>>(stP, g3, b3, sc3, 128, BB * NN / 8, 1.0f / ((float)BB * NN * KNN));
    edge_passB_kernel<<<BB * NN * 128 / 256, 256, 0, stream>>>(ymax, ymin, sc3, XT3, XC3, 128, BB * NN * 128);

    // layer 4: C=128 -> O=256 (bf16 MFMA dense T1/T2; output never feeds KNN)
    wprep4b_kernel<<<256 * 128 / 256, 256, 0, stream>>>(W4, Wa4b, Wd4b);
    xx_kernel<128><<<BB * NN / 256, 256, 0, stream>>>(XT3, xxb);
    for (int p = 0; p < 4; ++p) {
        knn_dist_kernel<128><<<dgrid, 256, 0, stream>>>(XC3, XT3, xxb, pd2, 2 * p);
        knn_sel_kernel<<<2 * NN / 4, 256, 0, stream>>>(pd2, idxb, 2 * p);
    }
    t2_mfma_kernel<<<BB * NN / 16, 256, 0, stream>>>(XT3, Wd4b, T2_4);   // overwrites XC1..3
    t2_mfma_kernel<<<BB * NN / 16, 256, 0, stream>>>(XT3, Wa4b, T1_4);   // into XT4 region
    edge_reduce_kernel<256, 4><<<BB * NN / 16, 256, 0, stream>>>(T1_4, T2_4, idxb, ymax, ymin, stP);
    finalize_stats_kernel<<<1, 256, 0, stream>>>(stP, g4, b4, sc4, 256, BB * NN / 16, 1.0f / ((float)BB * NN * KNN));
    edge_passB_kernel<<<BB * NN * 256 / 256, 256, 0, stream>>>(ymax, ymin, sc4, XT4, nullptr, 256, BB * NN * 256);

    // final: 512 -> 1024 (bf16 MFMA), BN over (B,N), leaky, max+mean over N
    w5b_kernel<<<1024 * 512 / 256, 256, 0, stream>>>(W5, W5b);
    final_mfmaA_kernel<<<BB * NN / 16, 256, 0, stream>>>(XT1, XT2, XT3, XT4, W5b, stP5);
    finalize_stats_kernel<<<4, 256, 0, stream>>>(stP5, g5, b5, sc5, 1024, BB * NN / 16, 1.0f / ((float)BB * NN));
    final_mfmaB_kernel<<<BB * NN / 16, 256, 0, stream>>>(XT1, XT2, XT3, XT4, W5b, sc5, pmax, psum);
    final_passC_kernel<<<(BB * 1024 + 255) / 256, 256, 0, stream>>>(pmax, psum, (float*)d_out);

    (void)in_sizes; (void)n_in; (void)out_size; (void)ws_size;
}

// Round 12
// 1246.642 us; speedup vs baseline: 1.1402x; 1.1402x over previous
//
#include <hip/hip_runtime.h>
#include <cfloat>

#define BB 8
#define NN 2048
#define KNN 20
#define EPSV 1e-5f
#define SLOPEV 0.2f

typedef short bf16x8 __attribute__((ext_vector_type(8)));   // 8 bf16 (4 VGPRs)
typedef float f32x4 __attribute__((ext_vector_type(4)));

__device__ __forceinline__ unsigned short f2b(float f) {
    unsigned u = __builtin_bit_cast(unsigned, f);
    unsigned r = (u + 0x7FFFu + ((u >> 16) & 1u)) >> 16;   // RNE
    return (unsigned short)r;
}
__device__ __forceinline__ short4 f2b4(float4 v) {
    short4 r;
    r.x = (short)f2b(v.x); r.y = (short)f2b(v.y);
    r.z = (short)f2b(v.z); r.w = (short)f2b(v.w);
    return r;
}

// ---------------- small prep kernels ----------------

__global__ void transpose0_kernel(const float* __restrict__ x, float* __restrict__ XT0) {
    int e = blockIdx.x * blockDim.x + threadIdx.x;
    if (e >= BB * NN * 3) return;
    int b = e / (NN * 3); int r = e - b * NN * 3; int n = r / 3; int c = r - n * 3;
    XT0[e] = x[((size_t)b * 3 + c) * NN + n];
}

__global__ void wprep_kernel(const float* __restrict__ W, float* __restrict__ WaT,
                             float* __restrict__ WdT, int C, int O) {
    int e = blockIdx.x * blockDim.x + threadIdx.x;
    if (e >= C * O) return;
    int c = e / O, o = e - c * O;
    float a = W[o * 2 * C + c];
    WaT[e] = a;
    WdT[e] = W[o * 2 * C + C + c] - a;
}

// W4 [256][256] -> packed MFMA-fragment-order bf16: Wp[nt<16][ks<4][lane<64][8]
// lane: arow=lane&15 (o=nt*16+arow), aq=lane>>4 (c=ks*32+aq*8+j). Wa from c,
// Wd = W[o][128+c]-W[o][c]. One contiguous 1KB burst per (nt,ks) wave-load.
// 4096 groups of 8 -> 4096 threads = 16 blocks of 256.
__global__ void w4pack_kernel(const float* __restrict__ W, short* __restrict__ WaP,
                              short* __restrict__ WdP) {
    int e = blockIdx.x * 256 + threadIdx.x;   // 0..4095
    int nt = e >> 8, ks = (e >> 6) & 3, lane = e & 63;
    int o = nt * 16 + (lane & 15);
    int cb = ks * 32 + (lane >> 4) * 8;
    short* pa = WaP + (size_t)e * 8;
    short* pd = WdP + (size_t)e * 8;
    #pragma unroll
    for (int j = 0; j < 8; ++j) {
        float a = W[o * 256 + cb + j];
        pa[j] = (short)f2b(a);
        pd[j] = (short)f2b(W[o * 256 + 128 + cb + j] - a);
    }
}

// W5 [1024][512] -> packed W5p[nt<64][ks<16][lane<64][8]; 65536 threads.
__global__ void w5pack_kernel(const float* __restrict__ W5, short* __restrict__ W5p) {
    int e = blockIdx.x * 256 + threadIdx.x;   // 0..65535
    int nt = e >> 10, ks = (e >> 6) & 15, lane = e & 63;
    int o = nt * 16 + (lane & 15);
    int cb = ks * 32 + (lane >> 4) * 8;
    short* p = W5p + (size_t)e * 8;
    #pragma unroll
    for (int j = 0; j < 8; ++j) p[j] = (short)f2b(W5[o * 512 + cb + j]);
}

// ---------------- per-point squared norm (matches dot-product partial order) ----

template <int C>
__global__ void xx_kernel(const float* __restrict__ XT, float* __restrict__ xx) {
    int e = blockIdx.x * blockDim.x + threadIdx.x;
    if (e >= BB * NN) return;
    const float* p = &XT[(size_t)e * C];
    float s;
    if constexpr (C % 4 == 0) {
        float s0 = 0, s1 = 0, s2 = 0, s3 = 0;
        for (int c = 0; c < C; c += 4) {
            float4 v = *(const float4*)(p + c);
            s0 += v.x * v.x; s1 += v.y * v.y; s2 += v.z * v.z; s3 += v.w * v.w;
        }
        s = (s0 + s1) + (s2 + s3);
    } else {
        s = p[0] * p[0];
        for (int c = 1; c < C; ++c) s += p[c] * p[c];
    }
    xx[e] = s;
}

// ---------------- KNN: tiled distance GEMM + register selection ----------------

template <int C>
__global__ __launch_bounds__(256) void knn_dist_kernel(
    const float* __restrict__ XC,   // [B][C][N]
    const float* __restrict__ XT,   // [B][N][C]
    const float* __restrict__ xx,   // [B][N]
    float* __restrict__ pd2,        // [2][N][N]
    int b0) {
    constexpr int BK = 16;
    __shared__ float As[BK][68];    // [c][n] (transposed on store)
    __shared__ alignas(16) float Bs[BK][64];   // [c][m]
    int mt = blockIdx.x, nt = blockIdx.y, bz = blockIdx.z;
    int b = b0 + bz;
    int n0 = nt * 64, m0 = mt * 64;
    int tid = threadIdx.x;
    int tn = tid >> 4, tm = tid & 15;
    float P[4][4][4];
    #pragma unroll
    for (int cl = 0; cl < 4; ++cl)
        #pragma unroll
        for (int i = 0; i < 4; ++i)
            #pragma unroll
            for (int j = 0; j < 4; ++j) P[cl][i][j] = 0.f;

    int arow = tid >> 2, acq = tid & 3;
    int brow = tid >> 4, bmq = tid & 15;
    for (int kb = 0; kb < C / BK; ++kb) {
        if (kb) __syncthreads();
        float4 av = *(const float4*)&XT[((size_t)b * NN + n0 + arow) * C + kb * BK + acq * 4];
        As[acq * 4 + 0][arow] = av.x; As[acq * 4 + 1][arow] = av.y;
        As[acq * 4 + 2][arow] = av.z; As[acq * 4 + 3][arow] = av.w;
        *(float4*)&Bs[brow][bmq * 4] =
            *(const float4*)&XC[((size_t)b * C + kb * BK + brow) * NN + m0 + bmq * 4];
        __syncthreads();
        #pragma unroll
        for (int c = 0; c < BK; ++c) {
            float4 a = *(const float4*)&As[c][tn * 4];
            float4 bv = *(const float4*)&Bs[c][tm * 4];
            int cl = c & 3;
            P[cl][0][0] += a.x * bv.x; P[cl][0][1] += a.x * bv.y; P[cl][0][2] += a.x * bv.z; P[cl][0][3] += a.x * bv.w;
            P[cl][1][0] += a.y * bv.x; P[cl][1][1] += a.y * bv.y; P[cl][1][2] += a.y * bv.z; P[cl][1][3] += a.y * bv.w;
            P[cl][2][0] += a.z * bv.x; P[cl][2][1] += a.z * bv.y; P[cl][2][2] += a.z * bv.z; P[cl][2][3] += a.z * bv.w;
            P[cl][3][0] += a.w * bv.x; P[cl][3][1] += a.w * bv.y; P[cl][3][2] += a.w * bv.z; P[cl][3][3] += a.w * bv.w;
        }
    }
    float4 xm = *(const float4*)&xx[(size_t)b * NN + m0 + tm * 4];
    #pragma unroll
    for (int i = 0; i < 4; ++i) {
        float xrn = xx[(size_t)b * NN + n0 + tn * 4 + i];
        float4 pd;
        float in0 = (P[0][i][0] + P[1][i][0]) + (P[2][i][0] + P[3][i][0]);
        float in1 = (P[0][i][1] + P[1][i][1]) + (P[2][i][1] + P[3][i][1]);
        float in2 = (P[0][i][2] + P[1][i][2]) + (P[2][i][2] + P[3][i][2]);
        float in3 = (P[0][i][3] + P[1][i][3]) + (P[2][i][3] + P[3][i][3]);
        pd.x = (2.0f * in0 - xrn) - xm.x;
        pd.y = (2.0f * in1 - xrn) - xm.y;
        pd.z = (2.0f * in2 - xrn) - xm.z;
        pd.w = (2.0f * in3 - xrn) - xm.w;
        *(float4*)&pd2[((size_t)bz * NN + n0 + tn * 4 + i) * NN + m0 + tm * 4] = pd;
    }
}

// strict > keeps earliest-inserted (lowest m) among equal values
#define INS(val, mm) do { \
    float _v = (val); int _m = (mm); \
    bool b1 = _v > v1, b2 = _v > v2, b3 = _v > v3, b4 = _v > v4; \
    i4 = b3 ? i3 : (b4 ? _m : i4);  v4 = b3 ? v3 : (b4 ? _v : v4); \
    i3 = b2 ? i2 : (b3 ? _m : i3);  v3 = b2 ? v2 : (b3 ? _v : v3); \
    i2 = b1 ? i1 : (b2 ? _m : i2);  v2 = b1 ? v1 : (b2 ? _v : v2); \
    i1 = b1 ? _m : i1;              v1 = b1 ? _v : v1; \
} while (0)

__device__ __forceinline__ void sel20_reg(const float4* pv, int lane, int* outp) {
    float v1 = -FLT_MAX, v2 = -FLT_MAX, v3 = -FLT_MAX, v4 = -FLT_MAX;
    int i1 = 0x7FFFFFFF, i2 = 0x7FFFFFFF, i3 = 0x7FFFFFFF, i4 = 0x7FFFFFFF;
    unsigned rm = 0;
    #pragma unroll
    for (int j = 0; j < 8; ++j) {
        int m0 = 4 * lane + 256 * j;
        INS(pv[j].x, m0); INS(pv[j].y, m0 + 1); INS(pv[j].z, m0 + 2); INS(pv[j].w, m0 + 3);
    }
    int depth = 4;
    for (int it = 0; it < KNN; ++it) {
        float bv = v1;
        #pragma unroll
        for (int off = 1; off < 64; off <<= 1) bv = fmaxf(bv, __shfl_xor(bv, off));
        int cand = (v1 == bv) ? i1 : 0x7FFFFFFF;
        int bi = cand;
        #pragma unroll
        for (int off = 1; off < 64; off <<= 1) bi = min(bi, __shfl_xor(bi, off));
        if (lane == 0) outp[it] = bi;
        if (v1 == bv && i1 == bi) {       // unique owner
            rm |= 1u << ((((unsigned)bi >> 6) & 0x1C) | ((unsigned)bi & 3));  // slot 4j+q
            v1 = v2; i1 = i2; v2 = v3; i2 = i3; v3 = v4; i3 = i4;
            v4 = -FLT_MAX; i4 = 0x7FFFFFFF;
            if (--depth == 0) {           // cache exhausted: exact rescan (rare)
                v1 = v2 = v3 = v4 = -FLT_MAX;
                i1 = i2 = i3 = i4 = 0x7FFFFFFF;
                #pragma unroll
                for (int j = 0; j < 8; ++j) {
                    int m0 = 4 * lane + 256 * j;
                    if (!(rm & (1u << (4 * j + 0)))) INS(pv[j].x, m0);
                    if (!(rm & (1u << (4 * j + 1)))) INS(pv[j].y, m0 + 1);
                    if (!(rm & (1u << (4 * j + 2)))) INS(pv[j].z, m0 + 2);
                    if (!(rm & (1u << (4 * j + 3)))) INS(pv[j].w, m0 + 3);
                }
                depth = 4;
            }
        }
    }
}

__global__ __launch_bounds__(256) void knn_sel_kernel(
    const float* __restrict__ pd2, int* __restrict__ idxb, int b0) {
    int tid = threadIdx.x, w = tid >> 6, lane = tid & 63;
    int rg = blockIdx.x * 4 + w;          // 0..4095 (2 batches)
    int bz = rg >> 11, n = rg & (NN - 1);
    const float* row = pd2 + ((size_t)bz * NN + n) * NN;
    float4 pv[8];
    #pragma unroll
    for (int j = 0; j < 8; ++j) pv[j] = *(const float4*)&row[4 * lane + 256 * j];
    int* outp = idxb + ((size_t)(b0 + bz) * NN + n) * KNN;
    sel20_reg(pv, lane, outp);
}

// Layer-1 (C=3) fused: pd computed inline in registers, same selection.
__global__ __launch_bounds__(256) void knn_c3_kernel(
    const float* __restrict__ XC,   // x: [B][3][N]
    const float* __restrict__ XT,   // XT0: [B][N][3]
    const float* __restrict__ xx, int* __restrict__ idxb) {
    int tid = threadIdx.x, w = tid >> 6, lane = tid & 63;
    int rg = blockIdx.x * 4 + w;          // 0..16383
    int b = rg >> 11, n = rg & (NN - 1);
    const float* xt0 = XT + ((size_t)b * NN + n) * 3;
    float s0 = xt0[0], s1 = xt0[1], s2 = xt0[2];
    float xrn = xx[(size_t)b * NN + n];
    float4 pv[8];
    #pragma unroll
    for (int j = 0; j < 8; ++j) {
        int m0 = 4 * lane + 256 * j;
        float4 v0 = *(const float4*)&XC[((size_t)b * 3 + 0) * NN + m0];
        float4 v1 = *(const float4*)&XC[((size_t)b * 3 + 1) * NN + m0];
        float4 v2 = *(const float4*)&XC[((size_t)b * 3 + 2) * NN + m0];
        float4 xm = *(const float4*)&xx[(size_t)b * NN + m0];
        float4 in;
        in.x = v0.x * s0; in.x += v1.x * s1; in.x += v2.x * s2;
        in.y = v0.y * s0; in.y += v1.y * s1; in.y += v2.y * s2;
        in.z = v0.z * s0; in.z += v1.z * s1; in.z += v2.z * s2;
        in.w = v0.w * s0; in.w += v1.w * s1; in.w += v2.w * s2;
        pv[j].x = (2.0f * in.x - xrn) - xm.x;
        pv[j].y = (2.0f * in.y - xrn) - xm.y;
        pv[j].z = (2.0f * in.z - xrn) - xm.z;
        pv[j].w = (2.0f * in.w - xrn) - xm.w;
    }
    int* outp = idxb + ((size_t)b * NN + n) * KNN;
    sel20_reg(pv, lane, outp);
}
#undef INS

// ---------------- dense T1/T2 precompute (fp32, layers 1-3) ----------------

template <int C, int O>
__global__ __launch_bounds__(256) void t1t2_gemm_kernel(
    const float* __restrict__ XT, const float* __restrict__ WaT,
    const float* __restrict__ WdT, float* __restrict__ T1, float* __restrict__ T2) {
    constexpr int CP = (C < 4) ? 4 : C;
    __shared__ alignas(16) float xt[64][CP];
    int p0 = blockIdx.x * 64;
    int tid = threadIdx.x;
    if constexpr (C % 4 == 0) {
        for (int e = tid; e < 64 * (C / 4); e += 256) {
            int r = e / (C / 4), q = e - r * (C / 4);
            *(float4*)&xt[r][q * 4] = *(const float4*)&XT[((size_t)p0 + r) * C + q * 4];
        }
    } else {
        for (int e = tid; e < 64 * C; e += 256) {
            int r = e / C, c = e - r * C;
            xt[r][c] = XT[((size_t)p0 + r) * C + c];
        }
    }
    __syncthreads();
    {
        constexpr int OQ = O / 4;
        constexpr int PS = 256 / OQ;
        constexpr int PPT = 64 / PS;
        int oq = tid % OQ, ps = tid / OQ;
        int o0 = oq * 4;
        float acc[PPT][4];
        #pragma unroll
        for (int t = 0; t < PPT; ++t) { acc[t][0] = 0; acc[t][1] = 0; acc[t][2] = 0; acc[t][3] = 0; }
        if constexpr (C % 4 == 0) {
            for (int c = 0; c < C; c += 4) {
                float4 w0 = *(const float4*)&WaT[(c + 0) * O + o0];
                float4 w1 = *(const float4*)&WaT[(c + 1) * O + o0];
                float4 w2 = *(const float4*)&WaT[(c + 2) * O + o0];
                float4 w3 = *(const float4*)&WaT[(c + 3) * O + o0];
                #pragma unroll
                for (int t = 0; t < PPT; ++t) {
                    float4 nv = *(const float4*)&xt[ps + t * PS][c];
                    acc[t][0] += nv.x * w0.x + nv.y * w1.x + nv.z * w2.x + nv.w * w3.x;
                    acc[t][1] += nv.x * w0.y + nv.y * w1.y + nv.z * w2.y + nv.w * w3.y;
                    acc[t][2] += nv.x * w0.z + nv.y * w1.z + nv.z * w2.z + nv.w * w3.z;
                    acc[t][3] += nv.x * w0.w + nv.y * w1.w + nv.z * w2.w + nv.w * w3.w;
                }
            }
        } else {
            for (int c = 0; c < C; ++c) {
                float4 w = *(const float4*)&WaT[c * O + o0];
                #pragma unroll
                for (int t = 0; t < PPT; ++t) {
                    float nv = xt[ps + t * PS][c];
                    acc[t][0] += nv * w.x; acc[t][1] += nv * w.y;
                    acc[t][2] += nv * w.z; acc[t][3] += nv * w.w;
                }
            }
        }
        #pragma unroll
        for (int t = 0; t < PPT; ++t)
            *(float4*)&T1[((size_t)p0 + ps + t * PS) * O + o0] =
                make_float4(acc[t][0], acc[t][1], acc[t][2], acc[t][3]);
    }
    {
        constexpr int PS2 = 256 / O;
        constexpr int PPT2 = 64 / PS2;
        int o = tid % O, ps = tid / O;
        float s[PPT2];
        #pragma unroll
        for (int t = 0; t < PPT2; ++t) s[t] = 0.f;
        for (int c = 0; c < C; ++c) {
            float w = WdT[c * O + o];
            #pragma unroll
            for (int t = 0; t < PPT2; ++t) s[t] += w * xt[ps + t * PS2][c];
        }
        #pragma unroll
        for (int t = 0; t < PPT2; ++t) T2[((size_t)p0 + ps + t * PS2) * O + o] = s[t];
    }
}

// ---------------- edge gather-reduce (DETERMINISTIC stats) --------

template <int O, int G>
__global__ __launch_bounds__(256) void edge_reduce_kernel(
    const float* __restrict__ T1, const float* __restrict__ T2,
    const int* __restrict__ idxb,
    float* __restrict__ ymaxb, float* __restrict__ yminb, float* __restrict__ stP) {
    constexpr int OQ = O / 4;
    constexpr int PTS = 256 / OQ;
    __shared__ int sidx[PTS][KNN];
    __shared__ alignas(16) float red[2][PTS][O];   // 2*PTS*O = 2048 floats
    int blk = blockIdx.x, tid = threadIdx.x;
    int oq = tid % OQ, ps = tid / OQ;
    int o0 = oq * 4;
    float4 as = make_float4(0, 0, 0, 0), aq = make_float4(0, 0, 0, 0);
    for (int g = 0; g < G; ++g) {
        int pbase = (blk * G + g) * PTS;
        if (g) __syncthreads();
        for (int e = tid; e < PTS * KNN; e += 256)
            sidx[e / KNN][e % KNN] = idxb[(size_t)(pbase + e / KNN) * KNN + (e % KNN)];
        __syncthreads();
        int p = pbase + ps;
        int b = p >> 11;
        float4 t2v = *(const float4*)&T2[(size_t)p * O + o0];
        float4 vmax = make_float4(-FLT_MAX, -FLT_MAX, -FLT_MAX, -FLT_MAX);
        float4 vmin = make_float4(FLT_MAX, FLT_MAX, FLT_MAX, FLT_MAX);
        float4 vs = make_float4(0, 0, 0, 0), vq = make_float4(0, 0, 0, 0);
        #pragma unroll 4
        for (int k = 0; k < KNN; ++k) {
            int r = (b << 11) + sidx[ps][k];
            float4 t1v = *(const float4*)&T1[(size_t)r * O + o0];
            float yx = t1v.x + t2v.x, yy = t1v.y + t2v.y;
            float yz = t1v.z + t2v.z, yw = t1v.w + t2v.w;
            vmax.x = fmaxf(vmax.x, yx); vmax.y = fmaxf(vmax.y, yy);
            vmax.z = fmaxf(vmax.z, yz); vmax.w = fmaxf(vmax.w, yw);
            vmin.x = fminf(vmin.x, yx); vmin.y = fminf(vmin.y, yy);
            vmin.z = fminf(vmin.z, yz); vmin.w = fminf(vmin.w, yw);
            vs.x += yx; vs.y += yy; vs.z += yz; vs.w += yw;
            vq.x += yx * yx; vq.y += yy * yy; vq.z += yz * yz; vq.w += yw * yw;
        }
        *(float4*)&ymaxb[(size_t)p * O + o0] = vmax;
        *(float4*)&yminb[(size_t)p * O + o0] = vmin;
        as.x += vs.x; as.y += vs.y; as.z += vs.z; as.w += vs.w;
        aq.x += vq.x; aq.y += vq.y; aq.z += vq.z; aq.w += vq.w;
    }
    __syncthreads();
    *(float4*)&red[0][ps][o0] = as;
    *(float4*)&red[1][ps][o0] = aq;
    __syncthreads();
    for (int e = tid; e < 2 * O; e += 256) {
        int pl = e / O, oo = e - pl * O;
        float s = red[pl][0][oo];
        #pragma unroll 4
        for (int j = 1; j < PTS; ++j) s += red[pl][j][oo];
        stP[(size_t)blk * 2 * O + e] = s;
    }
}

// ---------------- T = XT3 . W (bf16 MFMA, packed-fragment W), for T1_4/T2_4 ----

__global__ __launch_bounds__(256) void t2_mfma_kernel(
    const float* __restrict__ XT3, const short* __restrict__ Wp, float* __restrict__ T2) {
    __shared__ alignas(16) short A[16][136];
    int blk = blockIdx.x;           // BB*NN/16 = 1024
    int tid = threadIdx.x, w = tid >> 6, lane = tid & 63;
    int n0g = blk * 16;
    for (int ch = tid; ch < 512; ch += 256) {
        int r = ch >> 5, c4 = (ch & 31) << 2;
        float4 v = *(const float4*)&XT3[((size_t)n0g + r) * 128 + c4];
        *(short4*)&A[r][c4] = f2b4(v);
    }
    __syncthreads();
    int arow = lane & 15, aq = lane >> 4;
    bf16x8 af[4];
    #pragma unroll
    for (int ks = 0; ks < 4; ++ks)
        af[ks] = *(const bf16x8*)&A[arow][ks * 32 + aq * 8];
    for (int t = 0; t < 4; ++t) {
        int nt = w * 4 + t;
        f32x4 acc = {0.f, 0.f, 0.f, 0.f};
        const short* bp = Wp + ((size_t)(nt * 4) * 64 + lane) * 8;
        #pragma unroll
        for (int ks = 0; ks < 4; ++ks)
            acc = __builtin_amdgcn_mfma_f32_16x16x32_bf16(af[ks], *(const bf16x8*)(bp + ks * 512), acc, 0, 0, 0);
        #pragma unroll
        for (int r = 0; r < 4; ++r)
            T2[((size_t)n0g + aq * 4 + r) * 256 + nt * 16 + arow] = acc[r];
    }
}

// ---------------- BN finalize (fixed-order over per-block partials) ----------

__global__ void finalize_stats_kernel(const float* __restrict__ stP, const float* __restrict__ gg,
                                      const float* __restrict__ bb, float* __restrict__ scsh,
                                      int O, int nblk, float invM) {
    int o = blockIdx.x * blockDim.x + threadIdx.x;
    if (o >= O) return;
    float sa[8] = {0, 0, 0, 0, 0, 0, 0, 0}, qa[8] = {0, 0, 0, 0, 0, 0, 0, 0};
    int cp = 0;
    for (; cp + 8 <= nblk; cp += 8) {
        #pragma unroll
        for (int j = 0; j < 8; ++j) {
            sa[j] += stP[(size_t)(cp + j) * 2 * O + o];
            qa[j] += stP[(size_t)(cp + j) * 2 * O + O + o];
        }
    }
    for (; cp < nblk; ++cp) {
        sa[0] += stP[(size_t)cp * 2 * O + o];
        qa[0] += stP[(size_t)cp * 2 * O + O + o];
    }
    float s1 = ((sa[0] + sa[1]) + (sa[2] + sa[3])) + ((sa[4] + sa[5]) + (sa[6] + sa[7]));
    float s2 = ((qa[0] + qa[1]) + (qa[2] + qa[3])) + ((qa[4] + qa[5]) + (qa[6] + qa[7]));
    float mean = s1 * invM;
    float var = s2 * invM - mean * mean;
    float scale = gg[o] * rsqrtf(var + EPSV);
    float shift = bb[o] - mean * scale;
    scsh[o] = scale; scsh[O + o] = shift;
}

__global__ void edge_passB_kernel(const float* __restrict__ ymaxb, const float* __restrict__ yminb,
                                  const float* __restrict__ scsh, float* __restrict__ XTout,
                                  float* __restrict__ XCout, int O, int total) {
    int e = blockIdx.x * blockDim.x + threadIdx.x;
    if (e >= total) return;
    int o = e & (O - 1);
    float sc = scsh[o], sh = scsh[O + o];
    float y = (sc >= 0.0f) ? ymaxb[e] : yminb[e];   // monotone-affine max/min trick
    float z = sc * y + sh;
    float r = (z > 0.0f) ? z : SLOPEV * z;
    XTout[e] = r;
    if (XCout) {
        int n = (e / O) & (NN - 1);
        int bb_ = e / (O * NN);
        XCout[((size_t)bb_ * O + o) * NN + n] = r;
    }
}

// ---------------- final 512->1024 (bf16 MFMA, packed W5, dual-nt ILP) -----

__device__ __forceinline__ void stage_cat16_b(short (*A)[520], const float* __restrict__ XT1,
                                              const float* __restrict__ XT2, const float* __restrict__ XT3,
                                              const float* __restrict__ XT4, int n0g, int tid) {
    for (int ch = tid; ch < 16 * 16; ch += 256) { int r = ch >> 4, c4 = (ch & 15) << 2;
        *(short4*)&A[r][c4]       = f2b4(*(const float4*)&XT1[((size_t)n0g + r) * 64 + c4]); }
    for (int ch = tid; ch < 16 * 16; ch += 256) { int r = ch >> 4, c4 = (ch & 15) << 2;
        *(short4*)&A[r][64 + c4]  = f2b4(*(const float4*)&XT2[((size_t)n0g + r) * 64 + c4]); }
    for (int ch = tid; ch < 16 * 32; ch += 256) { int r = ch >> 5, c4 = (ch & 31) << 2;
        *(short4*)&A[r][128 + c4] = f2b4(*(const float4*)&XT3[((size_t)n0g + r) * 128 + c4]); }
    for (int ch = tid; ch < 16 * 64; ch += 256) { int r = ch >> 6, c4 = (ch & 63) << 2;
        *(short4*)&A[r][256 + c4] = f2b4(*(const float4*)&XT4[((size_t)n0g + r) * 256 + c4]); }
}

// Pass A: block-partial BN stats, non-atomic (slot = blk = point-tile index).
__global__ __launch_bounds__(256) void final_mfmaA_kernel(
    const float* __restrict__ XT1, const float* __restrict__ XT2, const float* __restrict__ XT3,
    const float* __restrict__ XT4, const short* __restrict__ W5p, float* __restrict__ stP5) {
    __shared__ alignas(16) short A[16][520];
    int blk = blockIdx.x;           // BB*NN/16 = 1024
    int tid = threadIdx.x, w = tid >> 6, lane = tid & 63;
    int n0g = blk * 16;
    stage_cat16_b(A, XT1, XT2, XT3, XT4, n0g, tid);
    __syncthreads();
    int arow = lane & 15, aq = lane >> 4;
    bf16x8 af[16];
    #pragma unroll
    for (int ks = 0; ks < 16; ++ks)
        af[ks] = *(const bf16x8*)&A[arow][ks * 32 + aq * 8];
    float* bp5 = stP5 + (size_t)blk * 2048;
    for (int tp = 0; tp < 8; ++tp) {
        int nt0 = w * 16 + 2 * tp, nt1 = nt0 + 1;
        f32x4 acc0 = {0.f, 0.f, 0.f, 0.f}, acc1 = {0.f, 0.f, 0.f, 0.f};
        const short* bp0 = W5p + ((size_t)(nt0 * 16) * 64 + lane) * 8;
        const short* bp1 = W5p + ((size_t)(nt1 * 16) * 64 + lane) * 8;
        #pragma unroll
        for (int ks = 0; ks < 16; ++ks) {
            bf16x8 b0 = *(const bf16x8*)(bp0 + ks * 512);
            bf16x8 b1 = *(const bf16x8*)(bp1 + ks * 512);
            acc0 = __builtin_amdgcn_mfma_f32_16x16x32_bf16(af[ks], b0, acc0, 0, 0, 0);
            acc1 = __builtin_amdgcn_mfma_f32_16x16x32_bf16(af[ks], b1, acc1, 0, 0, 0);
        }
        #pragma unroll
        for (int half = 0; half < 2; ++half) {
            f32x4 acc = half ? acc1 : acc0;
            int nt = half ? nt1 : nt0;
            float ls = (acc[0] + acc[1]) + (acc[2] + acc[3]);
            float lsq = (acc[0] * acc[0] + acc[1] * acc[1]) + (acc[2] * acc[2] + acc[3] * acc[3]);
            ls += __shfl_xor(ls, 16); ls += __shfl_xor(ls, 32);
            lsq += __shfl_xor(lsq, 16); lsq += __shfl_xor(lsq, 32);
            if (lane < 16) {
                int o = nt * 16 + lane;
                bp5[o] = ls; bp5[1024 + o] = lsq;
            }
        }
    }
}

__global__ __launch_bounds__(256) void final_mfmaB_kernel(
    const float* __restrict__ XT1, const float* __restrict__ XT2, const float* __restrict__ XT3,
    const float* __restrict__ XT4, const short* __restrict__ W5p, const float* __restrict__ scsh,
    float* __restrict__ pmax, float* __restrict__ psum) {
    __shared__ alignas(16) short A[16][520];
    int blk = blockIdx.x;           // 1024
    int tid = threadIdx.x, w = tid >> 6, lane = tid & 63;
    int n0g = blk * 16;
    stage_cat16_b(A, XT1, XT2, XT3, XT4, n0g, tid);
    __syncthreads();
    int arow = lane & 15, aq = lane >> 4;
    bf16x8 af[16];
    #pragma unroll
    for (int ks = 0; ks < 16; ++ks)
        af[ks] = *(const bf16x8*)&A[arow][ks * 32 + aq * 8];
    for (int tp = 0; tp < 8; ++tp) {
        int nt0 = w * 16 + 2 * tp, nt1 = nt0 + 1;
        f32x4 acc0 = {0.f, 0.f, 0.f, 0.f}, acc1 = {0.f, 0.f, 0.f, 0.f};
        const short* bp0 = W5p + ((size_t)(nt0 * 16) * 64 + lane) * 8;
        const short* bp1 = W5p + ((size_t)(nt1 * 16) * 64 + lane) * 8;
        #pragma unroll
        for (int ks = 0; ks < 16; ++ks) {
            bf16x8 b0 = *(const bf16x8*)(bp0 + ks * 512);
            bf16x8 b1 = *(const bf16x8*)(bp1 + ks * 512);
            acc0 = __builtin_amdgcn_mfma_f32_16x16x32_bf16(af[ks], b0, acc0, 0, 0, 0);
            acc1 = __builtin_amdgcn_mfma_f32_16x16x32_bf16(af[ks], b1, acc1, 0, 0, 0);
        }
        #pragma unroll
        for (int half = 0; half < 2; ++half) {
            f32x4 acc = half ? acc1 : acc0;
            int nt = half ? nt1 : nt0;
            int o = nt * 16 + arow;
            float sc = scsh[o], sh = scsh[1024 + o];
            float lmax = -FLT_MAX, lsm = 0.f;
            #pragma unroll
            for (int r = 0; r < 4; ++r) {
                float z = fmaf(sc, acc[r], sh);
                float l = (z > 0.0f) ? z : SLOPEV * z;
                lmax = fmaxf(lmax, l); lsm += l;
            }
            lmax = fmaxf(lmax, __shfl_xor(lmax, 16));
            lmax = fmaxf(lmax, __shfl_xor(lmax, 32));
            lsm += __shfl_xor(lsm, 16); lsm += __shfl_xor(lsm, 32);
            if (lane < 16) {
                pmax[(size_t)blk * 1024 + nt * 16 + lane] = lmax;
                psum[(size_t)blk * 1024 + nt * 16 + lane] = lsm;
            }
        }
    }
}

__global__ void final_passC_kernel(const float* __restrict__ pmax, const float* __restrict__ psum,
                                   float* __restrict__ out) {
    int e = blockIdx.x * blockDim.x + threadIdx.x;
    if (e >= BB * 1024) return;
    int b = e >> 10, o = e & 1023;
    float mx = -FLT_MAX, sm = 0;
    for (int j = 0; j < NN / 16; ++j) {
        size_t p = ((size_t)(b * (NN / 16) + j)) * 1024 + o;
        mx = fmaxf(mx, pmax[p]);
        sm += psum[p];
    }
    out[b * 2048 + o] = mx;
    out[b * 2048 + 1024 + o] = sm * (1.0f / NN);
}

// ---------------- launch ----------------

extern "C" void kernel_launch(void* const* d_in, const int* in_sizes, int n_in,
                              void* d_out, int out_size, void* d_ws, size_t ws_size,
                              hipStream_t stream) {
    const float* x  = (const float*)d_in[0];
    const float* W1 = (const float*)d_in[1];
    const float* W2 = (const float*)d_in[2];
    const float* W3 = (const float*)d_in[3];
    const float* W4 = (const float*)d_in[4];
    const float* W5 = (const float*)d_in[5];
    const float* g1 = (const float*)d_in[6];  const float* b1 = (const float*)d_in[7];
    const float* g2 = (const float*)d_in[8];  const float* b2 = (const float*)d_in[9];
    const float* g3 = (const float*)d_in[10]; const float* b3 = (const float*)d_in[11];
    const float* g4 = (const float*)d_in[12]; const float* b4 = (const float*)d_in[13];
    const float* g5 = (const float*)d_in[14]; const float* b5 = (const float*)d_in[15];

    float* ws = (float*)d_ws;
    size_t off = 0;
    float* XT0 = ws + off; off += (size_t)BB * NN * 3;
    float* XT1 = ws + off; off += (size_t)BB * NN * 64;
    float* XT2 = ws + off; off += (size_t)BB * NN * 64;
    float* XT3 = ws + off; off += (size_t)BB * NN * 128;
    float* XT4 = ws + off; off += (size_t)BB * NN * 256;
    float* XC1 = ws + off; off += (size_t)BB * NN * 64;
    float* XC2 = ws + off; off += (size_t)BB * NN * 64;
    float* XC3 = ws + off; off += (size_t)BB * NN * 128;
    float* ymax = ws + off; off += (size_t)BB * NN * 256;
    float* ymin = ws + off; off += (size_t)BB * NN * 256;
    int*   idxb = (int*)(ws + off); off += (size_t)BB * NN * KNN;
    float* xxb = ws + off; off += (size_t)BB * NN;
    float* WaT = ws + off; off += 128 * 256;
    float* WdT = ws + off; off += 128 * 256;
    short* WaP = (short*)(ws + off); off += 256 * 128 / 2;   // packed layer-4 Wa
    short* WdP = (short*)(ws + off); off += 256 * 128 / 2;   // packed layer-4 Wd
    short* W5p = (short*)(ws + off); off += 1024 * 512 / 2;  // packed W5
    float* stP = ws + off; off += 2048 * 256;          // per-block stat partials
    float* sc1 = ws + off; off += 2 * 64;
    float* sc2 = ws + off; off += 2 * 64;
    float* sc3 = ws + off; off += 2 * 128;
    float* sc4 = ws + off; off += 2 * 256;
    float* sc5 = ws + off; off += 2 * 1024;
    // aliases (lifetime-disjoint):
    float* T1f = XT4;                                  // layers 1-3 T1 (<=8MB)
    float* T2f = XT4 + (size_t)BB * NN * 128;          // layers 1-3 T2 (<=8MB)
    float* T1_4 = XT4;                                 // layer-4 T1 (16MB), consumed before passB writes XT4
    float* T2_4 = XC1;                                 // layer-4 T2 (16MB = XC1..3), dead after layer-4 knn
    float* pd2 = ymax;                                 // 2-batch pd tile (33.5MB = ymax+ymin)
    float* stP5 = ymax;                                // final-layer stat partials (2M floats), ymax dead then
    float* pmax = ymax;                                // final partials (after finalize consumed stP5)
    float* psum = ymin;

    transpose0_kernel<<<(BB * NN * 3 + 255) / 256, 256, 0, stream>>>(x, XT0);

    dim3 dgrid(NN / 64, NN / 64, 2);

    // layer 1: C=3 -> O=64   (x itself is the channel-major XC0)
    wprep_kernel<<<(3 * 64 + 255) / 256, 256, 0, stream>>>(W1, WaT, WdT, 3, 64);
    xx_kernel<3><<<BB * NN / 256, 256, 0, stream>>>(XT0, xxb);
    knn_c3_kernel<<<BB * NN / 4, 256, 0, stream>>>(x, XT0, xxb, idxb);
    t1t2_gemm_kernel<3, 64><<<BB * NN / 64, 256, 0, stream>>>(XT0, WaT, WdT, T1f, T2f);
    edge_reduce_kernel<64, 1><<<BB * NN / 16, 256, 0, stream>>>(T1f, T2f, idxb, ymax, ymin, stP);
    finalize_stats_kernel<<<1, 64, 0, stream>>>(stP, g1, b1, sc1, 64, BB * NN / 16, 1.0f / ((float)BB * NN * KNN));
    edge_passB_kernel<<<BB * NN * 64 / 256, 256, 0, stream>>>(ymax, ymin, sc1, XT1, XC1, 64, BB * NN * 64);

    // layer 2: C=64 -> O=64
    wprep_kernel<<<(64 * 64 + 255) / 256, 256, 0, stream>>>(W2, WaT, WdT, 64, 64);
    xx_kernel<64><<<BB * NN / 256, 256, 0, stream>>>(XT1, xxb);
    for (int p = 0; p < 4; ++p) {
        knn_dist_kernel<64><<<dgrid, 256, 0, stream>>>(XC1, XT1, xxb, pd2, 2 * p);
        knn_sel_kernel<<<2 * NN / 4, 256, 0, stream>>>(pd2, idxb, 2 * p);
    }
    t1t2_gemm_kernel<64, 64><<<BB * NN / 64, 256, 0, stream>>>(XT1, WaT, WdT, T1f, T2f);
    edge_reduce_kernel<64, 1><<<BB * NN / 16, 256, 0, stream>>>(T1f, T2f, idxb, ymax, ymin, stP);
    finalize_stats_kernel<<<1, 64, 0, stream>>>(stP, g2, b2, sc2, 64, BB * NN / 16, 1.0f / ((float)BB * NN * KNN));
    edge_passB_kernel<<<BB * NN * 64 / 256, 256, 0, stream>>>(ymax, ymin, sc2, XT2, XC2, 64, BB * NN * 64);

    // layer 3: C=64 -> O=128
    wprep_kernel<<<(64 * 128 + 255) / 256, 256, 0, stream>>>(W3, WaT, WdT, 64, 128);
    xx_kernel<64><<<BB * NN / 256, 256, 0, stream>>>(XT2, xxb);
    for (int p = 0; p < 4; ++p) {
        knn_dist_kernel<64><<<dgrid, 256, 0, stream>>>(XC2, XT2, xxb, pd2, 2 * p);
        knn_sel_kernel<<<2 * NN / 4, 256, 0, stream>>>(pd2, idxb, 2 * p);
    }
    t1t2_gemm_kernel<64, 128><<<BB * NN / 64, 256, 0, stream>>>(XT2, WaT, WdT, T1f, T2f);
    edge_reduce_kernel<128, 1><<<BB * NN / 8, 256, 0, stream>>>(T1f, T2f, idxb, ymax, ymin, stP);
    finalize_stats_kernel<<<1, 128, 0, stream>>>(stP, g3, b3, sc3, 128, BB * NN / 8, 1.0f / ((float)BB * NN * KNN));
    edge_passB_kernel<<<BB * NN * 128 / 256, 256, 0, stream>>>(ymax, ymin, sc3, XT3, XC3, 128, BB * NN * 128);

    // layer 4: C=128 -> O=256 (bf16 MFMA dense T1/T2 with packed W; output never feeds KNN)
    w4pack_kernel<<<4096 / 256, 256, 0, stream>>>(W4, WaP, WdP);   // 4096 groups, 1 thread each
    xx_kernel<128><<<BB * NN / 256, 256, 0, stream>>>(XT3, xxb);
    for (int p = 0; p < 4; ++p) {
        knn_dist_kernel<128><<<dgrid, 256, 0, stream>>>(XC3, XT3, xxb, pd2, 2 * p);
        knn_sel_kernel<<<2 * NN / 4, 256, 0, stream>>>(pd2, idxb, 2 * p);
    }
    t2_mfma_kernel<<<BB * NN / 16, 256, 0, stream>>>(XT3, WdP, T2_4);   // overwrites XC1..3
    t2_mfma_kernel<<<BB * NN / 16, 256, 0, stream>>>(XT3, WaP, T1_4);   // into XT4 region
    edge_reduce_kernel<256, 4><<<BB * NN / 16, 256, 0, stream>>>(T1_4, T2_4, idxb, ymax, ymin, stP);
    finalize_stats_kernel<<<1, 256, 0, stream>>>(stP, g4, b4, sc4, 256, BB * NN / 16, 1.0f / ((float)BB * NN * KNN));
    edge_passB_kernel<<<BB * NN * 256 / 256, 256, 0, stream>>>(ymax, ymin, sc4, XT4, nullptr, 256, BB * NN * 256);

    // final: 512 -> 1024 (bf16 MFMA, packed W5), BN over (B,N), leaky, max+mean over N
    w5pack_kernel<<<65536 / 256, 256, 0, stream>>>(W5, W5p);
    final_mfmaA_kernel<<<BB * NN / 16, 256, 0, stream>>>(XT1, XT2, XT3, XT4, W5p, stP5);
    finalize_stats_kernel<<<4, 256, 0, stream>>>(stP5, g5, b5, sc5, 1024, BB * NN / 16, 1.0f / ((float)BB * NN));
    final_mfmaB_kernel<<<BB * NN / 16, 256, 0, stream>>>(XT1, XT2, XT3, XT4, W5p, sc5, pmax, psum);
    final_passC_kernel<<<(BB * 1024 + 255) / 256, 256, 0, stream>>>(pmax, psum, (float*)d_out);

    (void)in_sizes; (void)n_in; (void)out_size; (void)ws_size;
}

// Round 15
// 1211.132 us; speedup vs baseline: 1.1736x; 1.0293x over previous
//
#include <hip/hip_runtime.h>
#include <cfloat>

#define BB 8
#define NN 2048
#define KNN 20
#define EPSV 1e-5f
#define SLOPEV 0.2f

typedef short bf16x8 __attribute__((ext_vector_type(8)));   // 8 bf16 (4 VGPRs)
typedef float f32x4 __attribute__((ext_vector_type(4)));

__device__ __forceinline__ unsigned short f2b(float f) {
    unsigned u = __builtin_bit_cast(unsigned, f);
    unsigned r = (u + 0x7FFFu + ((u >> 16) & 1u)) >> 16;   // RNE
    return (unsigned short)r;
}
__device__ __forceinline__ short4 f2b4(float4 v) {
    short4 r;
    r.x = (short)f2b(v.x); r.y = (short)f2b(v.y);
    r.z = (short)f2b(v.z); r.w = (short)f2b(v.w);
    return r;
}

// ---------------- small prep kernels ----------------

__global__ void transpose0_kernel(const float* __restrict__ x, float* __restrict__ XT0) {
    int e = blockIdx.x * blockDim.x + threadIdx.x;
    if (e >= BB * NN * 3) return;
    int b = e / (NN * 3); int r = e - b * NN * 3; int n = r / 3; int c = r - n * 3;
    XT0[e] = x[((size_t)b * 3 + c) * NN + n];
}

__global__ void wprep_kernel(const float* __restrict__ W, float* __restrict__ WaT,
                             float* __restrict__ WdT, int C, int O) {
    int e = blockIdx.x * blockDim.x + threadIdx.x;
    if (e >= C * O) return;
    int c = e / O, o = e - c * O;
    float a = W[o * 2 * C + c];
    WaT[e] = a;
    WdT[e] = W[o * 2 * C + C + c] - a;
}

// W4 [256][256] -> packed MFMA-fragment-order bf16: Wp[nt<16][ks<4][lane<64][8]
__global__ void w4pack_kernel(const float* __restrict__ W, short* __restrict__ WaP,
                              short* __restrict__ WdP) {
    int e = blockIdx.x * 256 + threadIdx.x;   // 0..4095
    int nt = e >> 8, ks = (e >> 6) & 3, lane = e & 63;
    int o = nt * 16 + (lane & 15);
    int cb = ks * 32 + (lane >> 4) * 8;
    short* pa = WaP + (size_t)e * 8;
    short* pd = WdP + (size_t)e * 8;
    #pragma unroll
    for (int j = 0; j < 8; ++j) {
        float a = W[o * 256 + cb + j];
        pa[j] = (short)f2b(a);
        pd[j] = (short)f2b(W[o * 256 + 128 + cb + j] - a);
    }
}

// W5 [1024][512] -> packed W5p[nt<64][ks<16][lane<64][8]; 65536 threads.
__global__ void w5pack_kernel(const float* __restrict__ W5, short* __restrict__ W5p) {
    int e = blockIdx.x * 256 + threadIdx.x;   // 0..65535
    int nt = e >> 10, ks = (e >> 6) & 15, lane = e & 63;
    int o = nt * 16 + (lane & 15);
    int cb = ks * 32 + (lane >> 4) * 8;
    short* p = W5p + (size_t)e * 8;
    #pragma unroll
    for (int j = 0; j < 8; ++j) p[j] = (short)f2b(W5[o * 512 + cb + j]);
}

// ---------------- per-point squared norm (matches dot-product partial order) ----

template <int C>
__global__ void xx_kernel(const float* __restrict__ XT, float* __restrict__ xx) {
    int e = blockIdx.x * blockDim.x + threadIdx.x;
    if (e >= BB * NN) return;
    const float* p = &XT[(size_t)e * C];
    float s;
    if constexpr (C % 4 == 0) {
        float s0 = 0, s1 = 0, s2 = 0, s3 = 0;
        for (int c = 0; c < C; c += 4) {
            float4 v = *(const float4*)(p + c);
            s0 += v.x * v.x; s1 += v.y * v.y; s2 += v.z * v.z; s3 += v.w * v.w;
        }
        s = (s0 + s1) + (s2 + s3);
    } else {
        s = p[0] * p[0];
        for (int c = 1; c < C; ++c) s += p[c] * p[c];
    }
    xx[e] = s;
}

// ---------------- KNN: tiled distance GEMM + register selection ----------------
// NOTE: the 16-term P accumulation must stay COMPLETE (verified contract).

template <int C>
__global__ __launch_bounds__(256) void knn_dist_kernel(
    const float* __restrict__ XC,   // [B][C][N]
    const float* __restrict__ XT,   // [B][N][C]
    const float* __restrict__ xx,   // [B][N]
    float* __restrict__ pd2,        // [2][N][N]
    int b0) {
    constexpr int BK = 16;
    __shared__ float As[BK][68];    // [c][n] (transposed on store)
    __shared__ alignas(16) float Bs[BK][64];   // [c][m]
    int mt = blockIdx.x, nt = blockIdx.y, bz = blockIdx.z;
    int b = b0 + bz;
    int n0 = nt * 64, m0 = mt * 64;
    int tid = threadIdx.x;
    int tn = tid >> 4, tm = tid & 15;
    float P[4][4][4];
    #pragma unroll
    for (int cl = 0; cl < 4; ++cl)
        #pragma unroll
        for (int i = 0; i < 4; ++i)
            #pragma unroll
            for (int j = 0; j < 4; ++j) P[cl][i][j] = 0.f;

    int arow = tid >> 2, acq = tid & 3;
    int brow = tid >> 4, bmq = tid & 15;
    for (int kb = 0; kb < C / BK; ++kb) {
        if (kb) __syncthreads();
        float4 av = *(const float4*)&XT[((size_t)b * NN + n0 + arow) * C + kb * BK + acq * 4];
        As[acq * 4 + 0][arow] = av.x; As[acq * 4 + 1][arow] = av.y;
        As[acq * 4 + 2][arow] = av.z; As[acq * 4 + 3][arow] = av.w;
        *(float4*)&Bs[brow][bmq * 4] =
            *(const float4*)&XC[((size_t)b * C + kb * BK + brow) * NN + m0 + bmq * 4];
        __syncthreads();
        #pragma unroll
        for (int c = 0; c < BK; ++c) {
            float4 a = *(const float4*)&As[c][tn * 4];
            float4 bv = *(const float4*)&Bs[c][tm * 4];
            int cl = c & 3;
            P[cl][0][0] += a.x * bv.x;
            P[cl][0][1] += a.x * bv.y;
            P[cl][0][2] += a.x * bv.z;
            P[cl][0][3] += a.x * bv.w;
            P[cl][1][0] += a.y * bv.x;
            P[cl][1][1] += a.y * bv.y;
            P[cl][1][2] += a.y * bv.z;
            P[cl][1][3] += a.y * bv.w;
            P[cl][2][0] += a.z * bv.x;
            P[cl][2][1] += a.z * bv.y;
            P[cl][2][2] += a.z * bv.z;
            P[cl][2][3] += a.z * bv.w;
            P[cl][3][0] += a.w * bv.x;
            P[cl][3][1] += a.w * bv.y;
            P[cl][3][2] += a.w * bv.z;
            P[cl][3][3] += a.w * bv.w;
        }
    }
    float4 xm = *(const float4*)&xx[(size_t)b * NN + m0 + tm * 4];
    #pragma unroll
    for (int i = 0; i < 4; ++i) {
        float xrn = xx[(size_t)b * NN + n0 + tn * 4 + i];
        float4 pd;
        float in0 = (P[0][i][0] + P[1][i][0]) + (P[2][i][0] + P[3][i][0]);
        float in1 = (P[0][i][1] + P[1][i][1]) + (P[2][i][1] + P[3][i][1]);
        float in2 = (P[0][i][2] + P[1][i][2]) + (P[2][i][2] + P[3][i][2]);
        float in3 = (P[0][i][3] + P[1][i][3]) + (P[2][i][3] + P[3][i][3]);
        pd.x = (2.0f * in0 - xrn) - xm.x;
        pd.y = (2.0f * in1 - xrn) - xm.y;
        pd.z = (2.0f * in2 - xrn) - xm.z;
        pd.w = (2.0f * in3 - xrn) - xm.w;
        *(float4*)&pd2[((size_t)bz * NN + n0 + tn * 4 + i) * NN + m0 + tm * 4] = pd;
    }
}

// strict > keeps earliest-inserted (lowest m) among equal values
#define INS(val, mm) do { \
    float _v = (val); int _m = (mm); \
    bool b1 = _v > v1, b2 = _v > v2, b3 = _v > v3, b4 = _v > v4; \
    i4 = b3 ? i3 : (b4 ? _m : i4);  v4 = b3 ? v3 : (b4 ? _v : v4); \
    i3 = b2 ? i2 : (b3 ? _m : i3);  v3 = b2 ? v2 : (b3 ? _v : v3); \
    i2 = b1 ? i1 : (b2 ? _m : i2);  v2 = b1 ? v1 : (b2 ? _v : v2); \
    i1 = b1 ? _m : i1;              v1 = b1 ? _v : v1; \
} while (0)

__device__ __forceinline__ void sel20_reg(const float4* pv, int lane, int* outp) {
    float v1 = -FLT_MAX, v2 = -FLT_MAX, v3 = -FLT_MAX, v4 = -FLT_MAX;
    int i1 = 0x7FFFFFFF, i2 = 0x7FFFFFFF, i3 = 0x7FFFFFFF, i4 = 0x7FFFFFFF;
    unsigned rm = 0;
    #pragma unroll
    for (int j = 0; j < 8; ++j) {
        int m0 = 4 * lane + 256 * j;
        INS(pv[j].x, m0); INS(pv[j].y, m0 + 1); INS(pv[j].z, m0 + 2); INS(pv[j].w, m0 + 3);
    }
    int depth = 4;
    for (int it = 0; it < KNN; ++it) {
        float bv = v1;
        #pragma unroll
        for (int off = 1; off < 64; off <<= 1) bv = fmaxf(bv, __shfl_xor(bv, off));
        int cand = (v1 == bv) ? i1 : 0x7FFFFFFF;
        int bi = cand;
        #pragma unroll
        for (int off = 1; off < 64; off <<= 1) bi = min(bi, __shfl_xor(bi, off));
        if (lane == 0) outp[it] = bi;
        if (v1 == bv && i1 == bi) {       // unique owner
            rm |= 1u << ((((unsigned)bi >> 6) & 0x1C) | ((unsigned)bi & 3));  // slot 4j+q
            v1 = v2; i1 = i2; v2 = v3; i2 = i3; v3 = v4; i3 = i4;
            v4 = -FLT_MAX; i4 = 0x7FFFFFFF;
            if (--depth == 0) {           // cache exhausted: exact rescan (rare)
                v1 = v2 = v3 = v4 = -FLT_MAX;
                i1 = i2 = i3 = i4 = 0x7FFFFFFF;
                #pragma unroll
                for (int j = 0; j < 8; ++j) {
                    int m0 = 4 * lane + 256 * j;
                    if (!(rm & (1u << (4 * j + 0)))) INS(pv[j].x, m0);
                    if (!(rm & (1u << (4 * j + 1)))) INS(pv[j].y, m0 + 1);
                    if (!(rm & (1u << (4 * j + 2)))) INS(pv[j].z, m0 + 2);
                    if (!(rm & (1u << (4 * j + 3)))) INS(pv[j].w, m0 + 3);
                }
                depth = 4;
            }
        }
    }
}

__global__ __launch_bounds__(256) void knn_sel_kernel(
    const float* __restrict__ pd2, int* __restrict__ idxb, int b0) {
    int tid = threadIdx.x, w = tid >> 6, lane = tid & 63;
    int rg = blockIdx.x * 4 + w;          // 0..4095 (2 batches)
    int bz = rg >> 11, n = rg & (NN - 1);
    const float* row = pd2 + ((size_t)bz * NN + n) * NN;
    float4 pv[8];
    #pragma unroll
    for (int j = 0; j < 8; ++j) pv[j] = *(const float4*)&row[4 * lane + 256 * j];
    int* outp = idxb + ((size_t)(b0 + bz) * NN + n) * KNN;
    sel20_reg(pv, lane, outp);
}

// Layer-1 (C=3) fused: pd computed inline in registers, same selection.
__global__ __launch_bounds__(256) void knn_c3_kernel(
    const float* __restrict__ XC,   // x: [B][3][N]
    const float* __restrict__ XT,   // XT0: [B][N][3]
    const float* __restrict__ xx, int* __restrict__ idxb) {
    int tid = threadIdx.x, w = tid >> 6, lane = tid & 63;
    int rg = blockIdx.x * 4 + w;          // 0..16383
    int b = rg >> 11, n = rg & (NN - 1);
    const float* xt0 = XT + ((size_t)b * NN + n) * 3;
    float s0 = xt0[0], s1 = xt0[1], s2 = xt0[2];
    float xrn = xx[(size_t)b * NN + n];
    float4 pv[8];
    #pragma unroll
    for (int j = 0; j < 8; ++j) {
        int m0 = 4 * lane + 256 * j;
        float4 v0 = *(const float4*)&XC[((size_t)b * 3 + 0) * NN + m0];
        float4 v1 = *(const float4*)&XC[((size_t)b * 3 + 1) * NN + m0];
        float4 v2 = *(const float4*)&XC[((size_t)b * 3 + 2) * NN + m0];
        float4 xm = *(const float4*)&xx[(size_t)b * NN + m0];
        float4 in;
        in.x = v0.x * s0; in.x += v1.x * s1; in.x += v2.x * s2;
        in.y = v0.y * s0; in.y += v1.y * s1; in.y += v2.y * s2;
        in.z = v0.z * s0; in.z += v1.z * s1; in.z += v2.z * s2;
        in.w = v0.w * s0; in.w += v1.w * s1; in.w += v2.w * s2;
        pv[j].x = (2.0f * in.x - xrn) - xm.x;
        pv[j].y = (2.0f * in.y - xrn) - xm.y;
        pv[j].z = (2.0f * in.z - xrn) - xm.z;
        pv[j].w = (2.0f * in.w - xrn) - xm.w;
    }
    int* outp = idxb + ((size_t)b * NN + n) * KNN;
    sel20_reg(pv, lane, outp);
}
#undef INS

// ---------------- dense T1/T2 precompute (fp32, layers 1-3) ----------------

template <int C, int O>
__global__ __launch_bounds__(256) void t1t2_gemm_kernel(
    const float* __restrict__ XT, const float* __restrict__ WaT,
    const float* __restrict__ WdT, float* __restrict__ T1, float* __restrict__ T2) {
    constexpr int CP = (C < 4) ? 4 : C;
    __shared__ alignas(16) float xt[64][CP];
    int p0 = blockIdx.x * 64;
    int tid = threadIdx.x;
    if constexpr (C % 4 == 0) {
        for (int e = tid; e < 64 * (C / 4); e += 256) {
            int r = e / (C / 4), q = e - r * (C / 4);
            *(float4*)&xt[r][q * 4] = *(const float4*)&XT[((size_t)p0 + r) * C + q * 4];
        }
    } else {
        for (int e = tid; e < 64 * C; e += 256) {
            int r = e / C, c = e - r * C;
            xt[r][c] = XT[((size_t)p0 + r) * C + c];
        }
    }
    __syncthreads();
    {
        constexpr int OQ = O / 4;
        constexpr int PS = 256 / OQ;
        constexpr int PPT = 64 / PS;
        int oq = tid % OQ, ps = tid / OQ;
        int o0 = oq * 4;
        float acc[PPT][4];
        #pragma unroll
        for (int t = 0; t < PPT; ++t) { acc[t][0] = 0; acc[t][1] = 0; acc[t][2] = 0; acc[t][3] = 0; }
        if constexpr (C % 4 == 0) {
            for (int c = 0; c < C; c += 4) {
                float4 w0 = *(const float4*)&WaT[(c + 0) * O + o0];
                float4 w1 = *(const float4*)&WaT[(c + 1) * O + o0];
                float4 w2 = *(const float4*)&WaT[(c + 2) * O + o0];
                float4 w3 = *(const float4*)&WaT[(c + 3) * O + o0];
                #pragma unroll
                for (int t = 0; t < PPT; ++t) {
                    float4 nv = *(const float4*)&xt[ps + t * PS][c];
                    acc[t][0] += nv.x * w0.x + nv.y * w1.x + nv.z * w2.x + nv.w * w3.x;
                    acc[t][1] += nv.x * w0.y + nv.y * w1.y + nv.z * w2.y + nv.w * w3.y;
                    acc[t][2] += nv.x * w0.z + nv.y * w1.z + nv.z * w2.z + nv.w * w3.z;
                    acc[t][3] += nv.x * w0.w + nv.y * w1.w + nv.z * w2.w + nv.w * w3.w;
                }
            }
        } else {
            for (int c = 0; c < C; ++c) {
                float4 w = *(const float4*)&WaT[c * O + o0];
                #pragma unroll
                for (int t = 0; t < PPT; ++t) {
                    float nv = xt[ps + t * PS][c];
                    acc[t][0] += nv * w.x; acc[t][1] += nv * w.y;
                    acc[t][2] += nv * w.z; acc[t][3] += nv * w.w;
                }
            }
        }
        #pragma unroll
        for (int t = 0; t < PPT; ++t)
            *(float4*)&T1[((size_t)p0 + ps + t * PS) * O + o0] =
                make_float4(acc[t][0], acc[t][1], acc[t][2], acc[t][3]);
    }
    {
        constexpr int PS2 = 256 / O;
        constexpr int PPT2 = 64 / PS2;
        int o = tid % O, ps = tid / O;
        float s[PPT2];
        #pragma unroll
        for (int t = 0; t < PPT2; ++t) s[t] = 0.f;
        for (int c = 0; c < C; ++c) {
            float w = WdT[c * O + o];
            #pragma unroll
            for (int t = 0; t < PPT2; ++t) s[t] += w * xt[ps + t * PS2][c];
        }
        #pragma unroll
        for (int t = 0; t < PPT2; ++t) T2[((size_t)p0 + ps + t * PS2) * O + o] = s[t];
    }
}

// ---------------- edge gather-reduce (DETERMINISTIC stats) --------

template <int O, int G>
__global__ __launch_bounds__(256) void edge_reduce_kernel(
    const float* __restrict__ T1, const float* __restrict__ T2,
    const int* __restrict__ idxb,
    float* __restrict__ ymaxb, float* __restrict__ yminb, float* __restrict__ stP) {
    constexpr int OQ = O / 4;
    constexpr int PTS = 256 / OQ;
    __shared__ int sidx[PTS][KNN];
    __shared__ alignas(16) float red[2][PTS][O];   // 2*PTS*O = 2048 floats
    int blk = blockIdx.x, tid = threadIdx.x;
    int oq = tid % OQ, ps = tid / OQ;
    int o0 = oq * 4;
    float4 as = make_float4(0, 0, 0, 0), aq = make_float4(0, 0, 0, 0);
    for (int g = 0; g < G; ++g) {
        int pbase = (blk * G + g) * PTS;
        if (g) __syncthreads();
        for (int e = tid; e < PTS * KNN; e += 256)
            sidx[e / KNN][e % KNN] = idxb[(size_t)(pbase + e / KNN) * KNN + (e % KNN)];
        __syncthreads();
        int p = pbase + ps;
        int b = p >> 11;
        float4 t2v = *(const float4*)&T2[(size_t)p * O + o0];
        float4 vmax = make_float4(-FLT_MAX, -FLT_MAX, -FLT_MAX, -FLT_MAX);
        float4 vmin = make_float4(FLT_MAX, FLT_MAX, FLT_MAX, FLT_MAX);
        float4 vs = make_float4(0, 0, 0, 0), vq = make_float4(0, 0, 0, 0);
        #pragma unroll 4
        for (int k = 0; k < KNN; ++k) {
            int r = (b << 11) + sidx[ps][k];
            float4 t1v = *(const float4*)&T1[(size_t)r * O + o0];
            float yx = t1v.x + t2v.x, yy = t1v.y + t2v.y;
            float yz = t1v.z + t2v.z, yw = t1v.w + t2v.w;
            vmax.x = fmaxf(vmax.x, yx); vmax.y = fmaxf(vmax.y, yy);
            vmax.z = fmaxf(vmax.z, yz); vmax.w = fmaxf(vmax.w, yw);
            vmin.x = fminf(vmin.x, yx); vmin.y = fminf(vmin.y, yy);
            vmin.z = fminf(vmin.z, yz); vmin.w = fminf(vmin.w, yw);
            vs.x += yx; vs.y += yy; vs.z += yz; vs.w += yw;
            vq.x += yx * yx; vq.y += yy * yy; vq.z += yz * yz; vq.w += yw * yw;
        }
        *(float4*)&ymaxb[(size_t)p * O + o0] = vmax;
        *(float4*)&yminb[(size_t)p * O + o0] = vmin;
        as.x += vs.x; as.y += vs.y; as.z += vs.z; as.w += vs.w;
        aq.x += vq.x; aq.y += vq.y; aq.z += vq.z; aq.w += vq.w;
    }
    __syncthreads();
    *(float4*)&red[0][ps][o0] = as;
    *(float4*)&red[1][ps][o0] = aq;
    __syncthreads();
    for (int e = tid; e < 2 * O; e += 256) {
        int pl = e / O, oo = e - pl * O;
        float s = red[pl][0][oo];
        #pragma unroll 4
        for (int j = 1; j < PTS; ++j) s += red[pl][j][oo];
        stP[(size_t)blk * 2 * O + e] = s;
    }
}

// ---------------- T = XT3 . W (bf16 MFMA, packed-fragment W), for T1_4/T2_4 ----

__global__ __launch_bounds__(256) void t2_mfma_kernel(
    const float* __restrict__ XT3, const short* __restrict__ Wp, float* __restrict__ T2) {
    __shared__ alignas(16) short A[16][136];
    int blk = blockIdx.x;           // BB*NN/16 = 1024
    int tid = threadIdx.x, w = tid >> 6, lane = tid & 63;
    int n0g = blk * 16;
    for (int ch = tid; ch < 512; ch += 256) {
        int r = ch >> 5, c4 = (ch & 31) << 2;
        float4 v = *(const float4*)&XT3[((size_t)n0g + r) * 128 + c4];
        *(short4*)&A[r][c4] = f2b4(v);
    }
    __syncthreads();
    int arow = lane & 15, aq = lane >> 4;
    bf16x8 af[4];
    #pragma unroll
    for (int ks = 0; ks < 4; ++ks)
        af[ks] = *(const bf16x8*)&A[arow][ks * 32 + aq * 8];
    for (int t = 0; t < 4; ++t) {
        int nt = w * 4 + t;
        f32x4 acc = {0.f, 0.f, 0.f, 0.f};
        const short* bp = Wp + ((size_t)(nt * 4) * 64 + lane) * 8;
        #pragma unroll
        for (int ks = 0; ks < 4; ++ks)
            acc = __builtin_amdgcn_mfma_f32_16x16x32_bf16(af[ks], *(const bf16x8*)(bp + ks * 512), acc, 0, 0, 0);
        #pragma unroll
        for (int r = 0; r < 4; ++r)
            T2[((size_t)n0g + aq * 4 + r) * 256 + nt * 16 + arow] = acc[r];
    }
}

// ---------------- BN finalize v3: parallel, BIT-IDENTICAL to R12 serial ------
// R12 summed 8 interleaved stripes sa[j] = sum_{cp = j, j+8, ...} (ascending)
// then combined ((s0+s1)+(s2+s3))+((s4+s5)+(s6+s7)). Here the 8 stripes go to
// 8 threads (same per-stripe ascending order) and thread j=0 applies the SAME
// combine tree -> every fp add identical to the proven-passing R12 kernel.
// 256 threads = 32 o's x 8 stripes; grid = ceil(O/32). Requires nblk % 8 == 0.

__global__ __launch_bounds__(256) void finalize_stats3_kernel(
    const float* __restrict__ stP, const float* __restrict__ gg,
    const float* __restrict__ bb, float* __restrict__ scsh,
    int O, int nblk, float invM) {
    int tid = threadIdx.x;
    int ol = tid >> 3;            // 0..31
    int j = tid & 7;              // stripe
    int o = blockIdx.x * 32 + ol;
    float s1 = 0.f, s2 = 0.f;
    if (o < O) {
        for (int cp = j; cp < nblk; cp += 8) {
            s1 += stP[(size_t)cp * 2 * O + o];
            s2 += stP[(size_t)cp * 2 * O + O + o];
        }
    }
    __shared__ float r1[32][8], r2[32][8];
    r1[ol][j] = s1; r2[ol][j] = s2;
    __syncthreads();
    if (j == 0 && o < O) {
        float a1 = ((r1[ol][0] + r1[ol][1]) + (r1[ol][2] + r1[ol][3]))
                 + ((r1[ol][4] + r1[ol][5]) + (r1[ol][6] + r1[ol][7]));
        float a2 = ((r2[ol][0] + r2[ol][1]) + (r2[ol][2] + r2[ol][3]))
                 + ((r2[ol][4] + r2[ol][5]) + (r2[ol][6] + r2[ol][7]));
        float mean = a1 * invM;
        float var = a2 * invM - mean * mean;
        float scale = gg[o] * rsqrtf(var + EPSV);
        scsh[o] = scale;
        scsh[O + o] = bb[o] - mean * scale;
    }
}

__global__ void edge_passB_kernel(const float* __restrict__ ymaxb, const float* __restrict__ yminb,
                                  const float* __restrict__ scsh, float* __restrict__ XTout,
                                  float* __restrict__ XCout, int O, int total) {
    int e = blockIdx.x * blockDim.x + threadIdx.x;
    if (e >= total) return;
    int o = e & (O - 1);
    float sc = scsh[o], sh = scsh[O + o];
    float y = (sc >= 0.0f) ? ymaxb[e] : yminb[e];   // monotone-affine max/min trick
    float z = sc * y + sh;
    float r = (z > 0.0f) ? z : SLOPEV * z;
    XTout[e] = r;
    if (XCout) {
        int n = (e / O) & (NN - 1);
        int bb_ = e / (O * NN);
        XCout[((size_t)bb_ * O + o) * NN + n] = r;
    }
}

// ---------------- final 512->1024 (bf16 MFMA, packed W5, dual-nt ILP) -----

__device__ __forceinline__ void stage_cat16_b(short (*A)[520], const float* __restrict__ XT1,
                                              const float* __restrict__ XT2, const float* __restrict__ XT3,
                                              const float* __restrict__ XT4, int n0g, int tid) {
    for (int ch = tid; ch < 16 * 16; ch += 256) { int r = ch >> 4, c4 = (ch & 15) << 2;
        *(short4*)&A[r][c4]       = f2b4(*(const float4*)&XT1[((size_t)n0g + r) * 64 + c4]); }
    for (int ch = tid; ch < 16 * 16; ch += 256) { int r = ch >> 4, c4 = (ch & 15) << 2;
        *(short4*)&A[r][64 + c4]  = f2b4(*(const float4*)&XT2[((size_t)n0g + r) * 64 + c4]); }
    for (int ch = tid; ch < 16 * 32; ch += 256) { int r = ch >> 5, c4 = (ch & 31) << 2;
        *(short4*)&A[r][128 + c4] = f2b4(*(const float4*)&XT3[((size_t)n0g + r) * 128 + c4]); }
    for (int ch = tid; ch < 16 * 64; ch += 256) { int r = ch >> 6, c4 = (ch & 63) << 2;
        *(short4*)&A[r][256 + c4] = f2b4(*(const float4*)&XT4[((size_t)n0g + r) * 256 + c4]); }
}

// Pass A: block-partial BN stats, non-atomic (slot = blk = point-tile index).
__global__ __launch_bounds__(256) void final_mfmaA_kernel(
    const float* __restrict__ XT1, const float* __restrict__ XT2, const float* __restrict__ XT3,
    const float* __restrict__ XT4, const short* __restrict__ W5p, float* __restrict__ stP5) {
    __shared__ alignas(16) short A[16][520];
    int blk = blockIdx.x;           // BB*NN/16 = 1024
    int tid = threadIdx.x, w = tid >> 6, lane = tid & 63;
    int n0g = blk * 16;
    stage_cat16_b(A, XT1, XT2, XT3, XT4, n0g, tid);
    __syncthreads();
    int arow = lane & 15, aq = lane >> 4;
    bf16x8 af[16];
    #pragma unroll
    for (int ks = 0; ks < 16; ++ks)
        af[ks] = *(const bf16x8*)&A[arow][ks * 32 + aq * 8];
    float* bp5 = stP5 + (size_t)blk * 2048;
    for (int tp = 0; tp < 8; ++tp) {
        int nt0 = w * 16 + 2 * tp, nt1 = nt0 + 1;
        f32x4 acc0 = {0.f, 0.f, 0.f, 0.f}, acc1 = {0.f, 0.f, 0.f, 0.f};
        const short* bp0 = W5p + ((size_t)(nt0 * 16) * 64 + lane) * 8;
        const short* bp1 = W5p + ((size_t)(nt1 * 16) * 64 + lane) * 8;
        #pragma unroll
        for (int ks = 0; ks < 16; ++ks) {
            bf16x8 b0 = *(const bf16x8*)(bp0 + ks * 512);
            bf16x8 b1 = *(const bf16x8*)(bp1 + ks * 512);
            acc0 = __builtin_amdgcn_mfma_f32_16x16x32_bf16(af[ks], b0, acc0, 0, 0, 0);
            acc1 = __builtin_amdgcn_mfma_f32_16x16x32_bf16(af[ks], b1, acc1, 0, 0, 0);
        }
        #pragma unroll
        for (int half = 0; half < 2; ++half) {
            f32x4 acc = half ? acc1 : acc0;
            int nt = half ? nt1 : nt0;
            float ls = (acc[0] + acc[1]) + (acc[2] + acc[3]);
            float lsq = (acc[0] * acc[0] + acc[1] * acc[1]) + (acc[2] * acc[2] + acc[3] * acc[3]);
            ls += __shfl_xor(ls, 16); ls += __shfl_xor(ls, 32);
            lsq += __shfl_xor(lsq, 16); lsq += __shfl_xor(lsq, 32);
            if (lane < 16) {
                int o = nt * 16 + lane;
                bp5[o] = ls; bp5[1024 + o] = lsq;
            }
        }
    }
}

__global__ __launch_bounds__(256) void final_mfmaB_kernel(
    const float* __restrict__ XT1, const float* __restrict__ XT2, const float* __restrict__ XT3,
    const float* __restrict__ XT4, const short* __restrict__ W5p, const float* __restrict__ scsh,
    float* __restrict__ pmax, float* __restrict__ psum) {
    __shared__ alignas(16) short A[16][520];
    int blk = blockIdx.x;           // 1024
    int tid = threadIdx.x, w = tid >> 6, lane = tid & 63;
    int n0g = blk * 16;
    stage_cat16_b(A, XT1, XT2, XT3, XT4, n0g, tid);
    __syncthreads();
    int arow = lane & 15, aq = lane >> 4;
    bf16x8 af[16];
    #pragma unroll
    for (int ks = 0; ks < 16; ++ks)
        af[ks] = *(const bf16x8*)&A[arow][ks * 32 + aq * 8];
    for (int tp = 0; tp < 8; ++tp) {
        int nt0 = w * 16 + 2 * tp, nt1 = nt0 + 1;
        f32x4 acc0 = {0.f, 0.f, 0.f, 0.f}, acc1 = {0.f, 0.f, 0.f, 0.f};
        const short* bp0 = W5p + ((size_t)(nt0 * 16) * 64 + lane) * 8;
        const short* bp1 = W5p + ((size_t)(nt1 * 16) * 64 + lane) * 8;
        #pragma unroll
        for (int ks = 0; ks < 16; ++ks) {
            bf16x8 b0 = *(const bf16x8*)(bp0 + ks * 512);
            bf16x8 b1 = *(const bf16x8*)(bp1 + ks * 512);
            acc0 = __builtin_amdgcn_mfma_f32_16x16x32_bf16(af[ks], b0, acc0, 0, 0, 0);
            acc1 = __builtin_amdgcn_mfma_f32_16x16x32_bf16(af[ks], b1, acc1, 0, 0, 0);
        }
        #pragma unroll
        for (int half = 0; half < 2; ++half) {
            f32x4 acc = half ? acc1 : acc0;
            int nt = half ? nt1 : nt0;
            int o = nt * 16 + arow;
            float sc = scsh[o], sh = scsh[1024 + o];
            float lmax = -FLT_MAX, lsm = 0.f;
            #pragma unroll
            for (int r = 0; r < 4; ++r) {
                float z = fmaf(sc, acc[r], sh);
                float l = (z > 0.0f) ? z : SLOPEV * z;
                lmax = fmaxf(lmax, l); lsm += l;
            }
            lmax = fmaxf(lmax, __shfl_xor(lmax, 16));
            lmax = fmaxf(lmax, __shfl_xor(lmax, 32));
            lsm += __shfl_xor(lsm, 16); lsm += __shfl_xor(lsm, 32);
            if (lane < 16) {
                pmax[(size_t)blk * 1024 + nt * 16 + lane] = lmax;
                psum[(size_t)blk * 1024 + nt * 16 + lane] = lsm;
            }
        }
    }
}

__global__ void final_passC_kernel(const float* __restrict__ pmax, const float* __restrict__ psum,
                                   float* __restrict__ out) {
    int e = blockIdx.x * blockDim.x + threadIdx.x;
    if (e >= BB * 1024) return;
    int b = e >> 10, o = e & 1023;
    float mx = -FLT_MAX, sm = 0;
    for (int j = 0; j < NN / 16; ++j) {
        size_t p = ((size_t)(b * (NN / 16) + j)) * 1024 + o;
        mx = fmaxf(mx, pmax[p]);
        sm += psum[p];
    }
    out[b * 2048 + o] = mx;
    out[b * 2048 + 1024 + o] = sm * (1.0f / NN);
}

// ---------------- launch ----------------

extern "C" void kernel_launch(void* const* d_in, const int* in_sizes, int n_in,
                              void* d_out, int out_size, void* d_ws, size_t ws_size,
                              hipStream_t stream) {
    const float* x  = (const float*)d_in[0];
    const float* W1 = (const float*)d_in[1];
    const float* W2 = (const float*)d_in[2];
    const float* W3 = (const float*)d_in[3];
    const float* W4 = (const float*)d_in[4];
    const float* W5 = (const float*)d_in[5];
    const float* g1 = (const float*)d_in[6];  const float* b1 = (const float*)d_in[7];
    const float* g2 = (const float*)d_in[8];  const float* b2 = (const float*)d_in[9];
    const float* g3 = (const float*)d_in[10]; const float* b3 = (const float*)d_in[11];
    const float* g4 = (const float*)d_in[12]; const float* b4 = (const float*)d_in[13];
    const float* g5 = (const float*)d_in[14]; const float* b5 = (const float*)d_in[15];

    float* ws = (float*)d_ws;
    size_t off = 0;
    float* XT0 = ws + off; off += (size_t)BB * NN * 3;
    float* XT1 = ws + off; off += (size_t)BB * NN * 64;
    float* XT2 = ws + off; off += (size_t)BB * NN * 64;
    float* XT3 = ws + off; off += (size_t)BB * NN * 128;
    float* XT4 = ws + off; off += (size_t)BB * NN * 256;
    float* XC1 = ws + off; off += (size_t)BB * NN * 64;
    float* XC2 = ws + off; off += (size_t)BB * NN * 64;
    float* XC3 = ws + off; off += (size_t)BB * NN * 128;
    float* ymax = ws + off; off += (size_t)BB * NN * 256;
    float* ymin = ws + off; off += (size_t)BB * NN * 256;
    int*   idxb = (int*)(ws + off); off += (size_t)BB * NN * KNN;
    float* xxb = ws + off; off += (size_t)BB * NN;
    float* WaT = ws + off; off += 128 * 256;
    float* WdT = ws + off; off += 128 * 256;
    short* WaP = (short*)(ws + off); off += 256 * 128 / 2;   // packed layer-4 Wa
    short* WdP = (short*)(ws + off); off += 256 * 128 / 2;   // packed layer-4 Wd
    short* W5p = (short*)(ws + off); off += 1024 * 512 / 2;  // packed W5
    float* stP = ws + off; off += 2048 * 256;          // per-block stat partials
    float* sc1 = ws + off; off += 2 * 64;
    float* sc2 = ws + off; off += 2 * 64;
    float* sc3 = ws + off; off += 2 * 128;
    float* sc4 = ws + off; off += 2 * 256;
    float* sc5 = ws + off; off += 2 * 1024;
    // aliases (lifetime-disjoint):
    float* T1f = XT4;                                  // layers 1-3 T1 (<=8MB)
    float* T2f = XT4 + (size_t)BB * NN * 128;          // layers 1-3 T2 (<=8MB)
    float* T1_4 = XT4;                                 // layer-4 T1 (16MB), consumed before passB writes XT4
    float* T2_4 = XC1;                                 // layer-4 T2 (16MB = XC1..3), dead after layer-4 knn
    float* pd2 = ymax;                                 // 2-batch pd tile (33.5MB = ymax+ymin)
    float* stP5 = ymax;                                // final-layer stat partials (2M floats), ymax dead then
    float* pmax = ymax;                                // final partials (after finalize consumed stP5)
    float* psum = ymin;

    transpose0_kernel<<<(BB * NN * 3 + 255) / 256, 256, 0, stream>>>(x, XT0);

    dim3 dgrid(NN / 64, NN / 64, 2);

    // layer 1: C=3 -> O=64   (x itself is the channel-major XC0)
    wprep_kernel<<<(3 * 64 + 255) / 256, 256, 0, stream>>>(W1, WaT, WdT, 3, 64);
    xx_kernel<3><<<BB * NN / 256, 256, 0, stream>>>(XT0, xxb);
    knn_c3_kernel<<<BB * NN / 4, 256, 0, stream>>>(x, XT0, xxb, idxb);
    t1t2_gemm_kernel<3, 64><<<BB * NN / 64, 256, 0, stream>>>(XT0, WaT, WdT, T1f, T2f);
    edge_reduce_kernel<64, 1><<<BB * NN / 16, 256, 0, stream>>>(T1f, T2f, idxb, ymax, ymin, stP);
    finalize_stats3_kernel<<<2, 256, 0, stream>>>(stP, g1, b1, sc1, 64, BB * NN / 16, 1.0f / ((float)BB * NN * KNN));
    edge_passB_kernel<<<BB * NN * 64 / 256, 256, 0, stream>>>(ymax, ymin, sc1, XT1, XC1, 64, BB * NN * 64);

    // layer 2: C=64 -> O=64
    wprep_kernel<<<(64 * 64 + 255) / 256, 256, 0, stream>>>(W2, WaT, WdT, 64, 64);
    xx_kernel<64><<<BB * NN / 256, 256, 0, stream>>>(XT1, xxb);
    for (int p = 0; p < 4; ++p) {
        knn_dist_kernel<64><<<dgrid, 256, 0, stream>>>(XC1, XT1, xxb, pd2, 2 * p);
        knn_sel_kernel<<<2 * NN / 4, 256, 0, stream>>>(pd2, idxb, 2 * p);
    }
    t1t2_gemm_kernel<64, 64><<<BB * NN / 64, 256, 0, stream>>>(XT1, WaT, WdT, T1f, T2f);
    edge_reduce_kernel<64, 1><<<BB * NN / 16, 256, 0, stream>>>(T1f, T2f, idxb, ymax, ymin, stP);
    finalize_stats3_kernel<<<2, 256, 0, stream>>>(stP, g2, b2, sc2, 64, BB * NN / 16, 1.0f / ((float)BB * NN * KNN));
    edge_passB_kernel<<<BB * NN * 64 / 256, 256, 0, stream>>>(ymax, ymin, sc2, XT2, XC2, 64, BB * NN * 64);

    // layer 3: C=64 -> O=128
    wprep_kernel<<<(64 * 128 + 255) / 256, 256, 0, stream>>>(W3, WaT, WdT, 64, 128);
    xx_kernel<64><<<BB * NN / 256, 256, 0, stream>>>(XT2, xxb);
    for (int p = 0; p < 4; ++p) {
        knn_dist_kernel<64><<<dgrid, 256, 0, stream>>>(XC2, XT2, xxb, pd2, 2 * p);
        knn_sel_kernel<<<2 * NN / 4, 256, 0, stream>>>(pd2, idxb, 2 * p);
    }
    t1t2_gemm_kernel<64, 128><<<BB * NN / 64, 256, 0, stream>>>(XT2, WaT, WdT, T1f, T2f);
    edge_reduce_kernel<128, 1><<<BB * NN / 8, 256, 0, stream>>>(T1f, T2f, idxb, ymax, ymin, stP);
    finalize_stats3_kernel<<<4, 256, 0, stream>>>(stP, g3, b3, sc3, 128, BB * NN / 8, 1.0f / ((float)BB * NN * KNN));
    edge_passB_kernel<<<BB * NN * 128 / 256, 256, 0, stream>>>(ymax, ymin, sc3, XT3, XC3, 128, BB * NN * 128);

    // layer 4: C=128 -> O=256 (bf16 MFMA dense T1/T2 with packed W; output never feeds KNN)
    w4pack_kernel<<<4096 / 256, 256, 0, stream>>>(W4, WaP, WdP);
    xx_kernel<128><<<BB * NN / 256, 256, 0, stream>>>(XT3, xxb);
    for (int p = 0; p < 4; ++p) {
        knn_dist_kernel<128><<<dgrid, 256, 0, stream>>>(XC3, XT3, xxb, pd2, 2 * p);
        knn_sel_kernel<<<2 * NN / 4, 256, 0, stream>>>(pd2, idxb, 2 * p);
    }
    t2_mfma_kernel<<<BB * NN / 16, 256, 0, stream>>>(XT3, WdP, T2_4);   // overwrites XC1..3
    t2_mfma_kernel<<<BB * NN / 16, 256, 0, stream>>>(XT3, WaP, T1_4);   // into XT4 region
    edge_reduce_kernel<256, 4><<<BB * NN / 16, 256, 0, stream>>>(T1_4, T2_4, idxb, ymax, ymin, stP);
    finalize_stats3_kernel<<<8, 256, 0, stream>>>(stP, g4, b4, sc4, 256, BB * NN / 16, 1.0f / ((float)BB * NN * KNN));
    edge_passB_kernel<<<BB * NN * 256 / 256, 256, 0, stream>>>(ymax, ymin, sc4, XT4, nullptr, 256, BB * NN * 256);

    // final: 512 -> 1024 (bf16 MFMA, packed W5), BN over (B,N), leaky, max+mean over N
    w5pack_kernel<<<65536 / 256, 256, 0, stream>>>(W5, W5p);
    final_mfmaA_kernel<<<BB * NN / 16, 256, 0, stream>>>(XT1, XT2, XT3, XT4, W5p, stP5);
    finalize_stats3_kernel<<<32, 256, 0, stream>>>(stP5, g5, b5, sc5, 1024, BB * NN / 16, 1.0f / ((float)BB * NN));
    final_mfmaB_kernel<<<BB * NN / 16, 256, 0, stream>>>(XT1, XT2, XT3, XT4, W5p, sc5, pmax, psum);
    final_passC_kernel<<<(BB * 1024 + 255) / 256, 256, 0, stream>>>(pmax, psum, (float*)d_out);

    (void)in_sizes; (void)n_in; (void)out_size; (void)ws_size;
}